// Round 9
// baseline (1260.785 us; speedup 1.0000x reference)
//
#include <hip/hip_runtime.h>
#include <hip/hip_bf16.h>

#define H 128
#define NSTEPS 8
#define DT_MAXF 0.125f
#define WAVES 4
#define PPW 16            // points per wave (one 16x16 MFMA N-tile)
#define PPB (WAVES*PPW)   // 64 points per block

typedef __attribute__((ext_vector_type(8))) short short8;   // 8 bf16 MFMA A/B frag
typedef __attribute__((ext_vector_type(4))) float floatx4;  // MFMA C/D frag
typedef __attribute__((ext_vector_type(2))) float f32x2;    // packed-FP32 pair (v_pk_*_f32)

__device__ __forceinline__ f32x2 sp2(float v) { return (f32x2){v, v}; }
__device__ __forceinline__ f32x2 fma2(f32x2 a, f32x2 b, f32x2 c) {
    return __builtin_elementwise_fma(a, b, c);              // -> v_pk_fma_f32
}
// tanh pair, merged-rcp form (R17): 1/(ea+1) = (eb+1)*rcp((ea+1)(eb+1)).
__device__ __forceinline__ f32x2 tanh2(f32x2 x) {
    f32x2 y = x * 2.8853900817779268f;
    f32x2 e; e[0] = __builtin_amdgcn_exp2f(y[0]); e[1] = __builtin_amdgcn_exp2f(y[1]);
    f32x2 ep = e + 1.0f;
    float rt = __builtin_amdgcn_rcpf(ep[0] * ep[1]);
    f32x2 eps = __builtin_shufflevector(ep, ep, 1, 0);
    f32x2 r = eps * sp2(rt);
    return fma2(sp2(-2.0f), r, sp2(1.0f));
}
__device__ __forceinline__ unsigned f2bf(float x) {           // fp32 -> bf16 bits, RNE
    unsigned u = __float_as_uint(x);
    return (u + 0x7FFFu + ((u >> 16) & 1u)) >> 16;
}
__device__ __forceinline__ unsigned pk2(float a, float b) {   // packed bf16 cvt
    union { __hip_bfloat162 h; unsigned u; } U;
    U.h = __float22bfloat162_rn(make_float2(a, b));
    return U.u;
}
__device__ __forceinline__ unsigned pkv(f32x2 v) { return pk2(v[0], v[1]); }
__device__ __forceinline__ short8 mk8(unsigned a, unsigned b, unsigned c, unsigned d) {
    union { unsigned u[4]; short8 s; } U;
    U.u[0] = a; U.u[1] = b; U.u[2] = c; U.u[3] = d; return U.s;
}
// xyzt B-frag, hi/lo split bf16. Lane q=0 carries hi+lo, q=1 carries hi, q>=2 zero.
__device__ __forceinline__ short8 xyzt_frag(float x, float y, float z, float t, int q) {
    unsigned hx = f2bf(x), hy = f2bf(y), hz = f2bf(z), ht = f2bf(t);
    float lx = x - __uint_as_float(hx << 16);
    float ly = y - __uint_as_float(hy << 16);
    float lz = z - __uint_as_float(hz << 16);
    float lt = t - __uint_as_float(ht << 16);
    unsigned w0 = hx | (hy << 16), w1 = hz | (ht << 16);
    unsigned w2 = pk2(lx, ly),     w3 = pk2(lz, lt);
    union { unsigned u[4]; short8 s; } F;
    F.u[0] = (q < 2)  ? w0 : 0u;
    F.u[1] = (q < 2)  ? w1 : 0u;
    F.u[2] = (q == 0) ? w2 : 0u;
    F.u[3] = (q == 0) ? w3 : 0u;
    return F.s;
}

// ---- R18 pre-pass: counting-sort points by needed-step bucket ----
// b = ceil(|t1-t2|*8) in [0,8]. Sorted waves share a bucket -> the main
// kernel's wave-uniform break skips finished steps (exact no-ops, so output
// is BITWISE IDENTICAL for any permutation; sorting is perf-only).
__device__ __forceinline__ int step_bucket(float t1v, float t2v) {
    float off = fabsf(t1v - t2v);
    int b = (int)ceilf(off * 8.0f);
    return min(max(b, 0), 8);
}
__global__ void prep_zero(unsigned* cnt) {
    if (threadIdx.x < 18) cnt[threadIdx.x] = 0u;
}
__global__ void prep_hist(const float* __restrict__ t1g, const float* __restrict__ t2g,
                          unsigned* cnt, int N) {
    int i = blockIdx.x * 256 + threadIdx.x;
    if (i < N) atomicAdd(&cnt[step_bucket(t1g[i], t2g[i])], 1u);
}
__global__ void prep_prefix(unsigned* cnt) {
    if (threadIdx.x == 0) {
        unsigned run = 0;
        for (int b = 0; b < 9; ++b) { unsigned c = cnt[b]; cnt[9 + b] = run; run += c; }
    }
}
__global__ void prep_scatter(const float* __restrict__ t1g, const float* __restrict__ t2g,
                             unsigned* cnt, int* __restrict__ perm, int N) {
    int i = blockIdx.x * 256 + threadIdx.x;
    if (i < N) {
        int b = step_bucket(t1g[i], t2g[i]);
        unsigned slot = atomicAdd(&cnt[9 + b], 1u);   // unique slot in bucket range
        perm[slot] = i;
    }
}

// R12: L1/L2/L3 on the MFMA pipe (pi-permuted k; zero cross-lane repack).
// R13-R16: occupancy arc NULL (3 waves == 2 waves on VALUBusy/MfmaUtil).
// R17: VALU shaves ~1% -- per-step work is near-irreducible (512 tanh/point/
//   step + bf16 packing are inherent; issue port ~90% busy).
// R18: cut STEPS EXECUTED instead. Points sorted by needed-step bucket
//   (pre-pass above); wave-uniform `break` when all 16 points of the wave
//   have off_==0 (their remaining steps are exact no-ops -> bitwise-same
//   output). Mean needed steps = 4.5 of 8 -> ~40% main-loop work cut.
//   No __syncthreads in the step loop, so waves exit independently.
__global__ __launch_bounds__(256, 2)
void velwarp(const float* __restrict__ code, const float* __restrict__ pos,
             const float* __restrict__ t1g, const float* __restrict__ t2g,
             const float* __restrict__ W1, const float* __restrict__ b1,
             const float* __restrict__ W2, const float* __restrict__ b2,
             const float* __restrict__ W3, const float* __restrict__ b3,
             float* __restrict__ out, const int* __restrict__ perm, int N)
{
    __shared__ __align__(16) uint4 WbufU[2048];   // 32KB: W1 fp32 staging (init) then W2 bf16 frags
    __shared__ __align__(16) uint4 W1AU[8*64];    // 8KB : layer-1 A-frags (xyzt rows, hi/lo split)
    __shared__ __align__(16) uint4 W3AU[4*64];    // 4KB : layer-3 A-frags (W3^T, pi-permuted)
    __shared__ __align__(16) floatx4 WdX4[32];    // W1[64][u] in C/D order (= row-linear)
    __shared__ __align__(16) floatx4 WdY4[32];    // W1[65][u]
    __shared__ __align__(16) floatx4 WdZ4[32];    // W1[66][u]
    __shared__ __align__(16) floatx4 b2C4[32];    // b2 in C/D order

    const int tid = threadIdx.x;
    const int L   = tid & 63;
    const int m   = L & 15;      // this lane's point (C/D col)
    const int q   = L >> 4;      // C/D row group = q*4+reg; B-frag k-quad
    const int pb  = blockIdx.x * PPB + (tid >> 6) * PPW;
    const int p   = perm ? perm[pb + m] : (pb + m);   // global point index

    // ---- stage W1 rows [0:64) as fp32 into Wbuf
    {
        const float4* s4 = (const float4*)W1;
        float4* d4 = (float4*)WbufU;
        #pragma unroll 4
        for (int i = tid; i < (64*H)/4; i += 256) d4[i] = s4[i];
    }
    // ---- layer-1 A-frags: tile t, lane l: row u = 16t+(l&15); hi/lo split
    for (int e = tid; e < 512; e += 256) {
        int t = e >> 6, l = e & 63;
        int u = t*16 + (l & 15), qq = l >> 4;
        unsigned hb[4], lb[4];
        #pragma unroll
        for (int c = 0; c < 4; ++c) {
            float wv = W1[(64 + c)*H + u];
            unsigned hh = f2bf(wv);
            float wl = wv - __uint_as_float(hh << 16);
            hb[c] = hh; lb[c] = f2bf(wl);
        }
        unsigned hi01 = hb[0] | (hb[1] << 16), hi23 = hb[2] | (hb[3] << 16);
        unsigned lo01 = lb[0] | (lb[1] << 16), lo23 = lb[2] | (lb[3] << 16);
        uint4 o;
        if (qq == 0)      o = make_uint4(hi01, hi23, hi01, hi23);
        else if (qq == 1) o = make_uint4(lo01, lo23, 0u, 0u);
        else              o = make_uint4(0u, 0u, 0u, 0u);
        W1AU[e] = o;
    }
    // ---- layer-3 A-frags: slice s, lane l: row a = l&15 (rows 3..15 zero)
    for (int e = tid; e < 256; e += 256) {
        int s = e >> 6, l = e & 63;
        int a = l & 15, qq = l >> 4;
        uint4 o = make_uint4(0u, 0u, 0u, 0u);
        if (a < 3) {
            int u0 = s*32 + qq*4, u1 = u0 + 16;
            o.x = f2bf(W3[(u0+0)*3+a]) | (f2bf(W3[(u0+1)*3+a]) << 16);
            o.y = f2bf(W3[(u0+2)*3+a]) | (f2bf(W3[(u0+3)*3+a]) << 16);
            o.z = f2bf(W3[(u1+0)*3+a]) | (f2bf(W3[(u1+1)*3+a]) << 16);
            o.w = f2bf(W3[(u1+2)*3+a]) | (f2bf(W3[(u1+3)*3+a]) << 16);
        }
        W3AU[e] = o;
    }
    if (tid < 32) {
        WdX4[tid] = ((const floatx4*)(W1 + (size_t)64*H))[tid];
        WdY4[tid] = ((const floatx4*)(W1 + (size_t)65*H))[tid];
        WdZ4[tid] = ((const floatx4*)(W1 + (size_t)66*H))[tid];
        b2C4[tid] = ((const floatx4*)b2)[tid];
    }
    __syncthreads();

    // ---- base1C[t] (fp32, C/D layout): u = 16t + 4q + reg
    floatx4 base1C[8];
    {
        #pragma unroll
        for (int t = 0; t < 8; ++t) base1C[t] = *(const floatx4*)&b1[t*16 + q*4];
        const float* Ws = (const float*)WbufU;
        const float* crow = code + (size_t)p * 64;
        for (int i = 0; i < 64; ++i) {
            f32x2 c = sp2(crow[i]);
            #pragma unroll
            for (int t = 0; t < 8; ++t) {
                floatx4 wq = *(const floatx4*)&Ws[i*H + t*16 + q*4];
                base1C[t].xy = fma2(c, wq.xy, base1C[t].xy);
                base1C[t].zw = fma2(c, wq.zw, base1C[t].zw);
            }
        }
    }
    __syncthreads();   // all lanes done reading W1 fp32 before repack

    // ---- pack W2 -> bf16 A-frags with pi-permuted k
    for (int ch = tid; ch < 2048; ch += 256) {
        int ln = ch & 63, ts = ch >> 6;
        int s = ts & 3, t = ts >> 2;
        int qq = ln >> 4, n = t*16 + (ln & 15);
        int u0 = s*32 + qq*4, u1 = u0 + 16;
        unsigned w0 = f2bf(W2[(u0+0)*H+n]) | (f2bf(W2[(u0+1)*H+n]) << 16);
        unsigned w1 = f2bf(W2[(u0+2)*H+n]) | (f2bf(W2[(u0+3)*H+n]) << 16);
        unsigned w2 = f2bf(W2[(u1+0)*H+n]) | (f2bf(W2[(u1+1)*H+n]) << 16);
        unsigned w3v = f2bf(W2[(u1+2)*H+n]) | (f2bf(W2[(u1+3)*H+n]) << 16);
        WbufU[ch] = make_uint4(w0, w1, w2, w3v);
    }

    // ---- per-lane point state
    float px_ = pos[p*3+0], py_ = pos[p*3+1], pz_ = pos[p*3+2];
    float tc_ = t1g[p];
    float off_ = tc_ - t2g[p];
    // deform D as 3 packed col-pairs + 3 scalars (cols 0,1 | col 2), row o
    f32x2 Dp[3]; float Ds[3];
    Dp[0] = (f32x2){1.f, 0.f}; Ds[0] = 0.f;
    Dp[1] = (f32x2){0.f, 1.f}; Ds[1] = 0.f;
    Dp[2] = (f32x2){0.f, 0.f}; Ds[2] = 1.f;
    const float b30 = b3[0], b31 = b3[1], b32 = b3[2];
    __syncthreads();

    const short8* Bf   = (const short8*)WbufU;
    const short8* W1Af = (const short8*)W1AU;
    const short8* W3Af = (const short8*)W3AU;
    const floatx4 Z4 = {0.f, 0.f, 0.f, 0.f};

    for (int step = 0; step < NSTEPS; ++step) {
        // R18: all remaining steps for this wave's 16 points are exact no-ops
        // (off_==0 -> dt_=0). Wave-uniform skip; bitwise-same output.
        if (!__any(off_ != 0.0f)) break;

        // ======== eval A: v(x,t) ========
        float vAx, vAy, vAz;
        {
            short8 xf = xyzt_frag(px_, py_, pz_, tc_, q);
            floatx4 z[8];
            #pragma unroll
            for (int t = 0; t < 8; ++t)
                z[t] = __builtin_amdgcn_mfma_f32_16x16x32_bf16(W1Af[t*64 + L], xf, base1C[t], 0, 0, 0);
            short8 fh[4];
            #pragma unroll
            for (int s = 0; s < 4; ++s) {
                f32x2 a0 = tanh2(z[2*s].xy),   a1 = tanh2(z[2*s].zw);
                f32x2 c0 = tanh2(z[2*s+1].xy), c1 = tanh2(z[2*s+1].zw);
                fh[s] = mk8(pkv(a0), pkv(a1), pkv(c0), pkv(c1));
            }
            __builtin_amdgcn_sched_barrier(0);
            // quarter qi covers tiles 2qi,2qi+1 == L3 slice qi
            floatx4 vacc = Z4;
            #pragma unroll
            for (int qi = 0; qi < 4; ++qi) {
                const int T0 = 2*qi, T1 = 2*qi + 1;
                floatx4 acc0 = __builtin_amdgcn_mfma_f32_16x16x32_bf16(
                    Bf[(T0*4 + 0)*64 + L], fh[0], b2C4[T0*4 + q], 0, 0, 0);
                floatx4 acc1 = __builtin_amdgcn_mfma_f32_16x16x32_bf16(
                    Bf[(T1*4 + 0)*64 + L], fh[0], b2C4[T1*4 + q], 0, 0, 0);
                #pragma unroll
                for (int s = 1; s < 4; ++s) {
                    acc0 = __builtin_amdgcn_mfma_f32_16x16x32_bf16(Bf[(T0*4 + s)*64 + L], fh[s], acc0, 0, 0, 0);
                    acc1 = __builtin_amdgcn_mfma_f32_16x16x32_bf16(Bf[(T1*4 + s)*64 + L], fh[s], acc1, 0, 0, 0);
                }
                f32x2 e00 = tanh2(acc0.xy), e01 = tanh2(acc0.zw);
                f32x2 e10 = tanh2(acc1.xy), e11 = tanh2(acc1.zw);
                short8 ef = mk8(pkv(e00), pkv(e01), pkv(e10), pkv(e11));
                vacc = __builtin_amdgcn_mfma_f32_16x16x32_bf16(W3Af[qi*64 + L], ef, vacc, 0, 0, 0);
                __builtin_amdgcn_sched_barrier(0);
            }
            vAx = __shfl(vacc[0], m, 64);
            vAy = __shfl(vacc[1], m, 64);
            vAz = __shfl(vacc[2], m, 64);
        }

        float dt_ = copysignf(fminf(fabsf(off_), DT_MAXF), off_);
        float hd = 0.5f * dt_;
        float mx = px_ - hd*(vAx + b30);
        float my = py_ - hd*(vAy + b31);
        float mz = pz_ - hd*(vAz + b32);
        float tm = tc_ - hd;

        // ======== eval B: v + Jacobian at midpoint ========
        float vx, vy, vz;
        floatx4 V = Z4, J0 = Z4, J1 = Z4, J2 = Z4;
        {
            short8 xf = xyzt_frag(mx, my, mz, tm, q);
            floatx4 z[8];
            #pragma unroll
            for (int t = 0; t < 8; ++t)
                z[t] = __builtin_amdgcn_mfma_f32_16x16x32_bf16(W1Af[t*64 + L], xf, base1C[t], 0, 0, 0);
            short8 fh[4], fd0[4], fd1[4], fd2[4];
            #pragma unroll
            for (int s = 0; s < 4; ++s) {
                unsigned uh[4], u0[4], u1[4], u2[4];
                #pragma unroll
                for (int hf = 0; hf < 2; ++hf) {
                    int t = 2*s + hf;
                    f32x2 h0 = tanh2(z[t].xy), h1 = tanh2(z[t].zw);
                    f32x2 s0 = fma2(-h0, h0, sp2(1.0f));
                    f32x2 s1 = fma2(-h1, h1, sp2(1.0f));
                    floatx4 wx = WdX4[t*4 + q], wy = WdY4[t*4 + q], wz = WdZ4[t*4 + q];
                    uh[2*hf+0] = pkv(h0);         uh[2*hf+1] = pkv(h1);
                    u0[2*hf+0] = pkv(s0 * wx.xy); u0[2*hf+1] = pkv(s1 * wx.zw);
                    u1[2*hf+0] = pkv(s0 * wy.xy); u1[2*hf+1] = pkv(s1 * wy.zw);
                    u2[2*hf+0] = pkv(s0 * wz.xy); u2[2*hf+1] = pkv(s1 * wz.zw);
                }
                fh[s]  = mk8(uh[0], uh[1], uh[2], uh[3]);
                fd0[s] = mk8(u0[0], u0[1], u0[2], u0[3]);
                fd1[s] = mk8(u1[0], u1[1], u1[2], u1[3]);
                fd2[s] = mk8(u2[0], u2[1], u2[2], u2[3]);
            }
            __builtin_amdgcn_sched_barrier(0);
            // quarter qi = one L3 slice: tiles 2qi,2qi+1, all 4 chains, post,
            // 4 L3 MFMAs.
            #pragma unroll
            for (int qi = 0; qi < 4; ++qi) {
                const int T0 = 2*qi, T1 = 2*qi + 1;
                floatx4 aH0, aH1, aD00, aD01, aD10, aD11, aD20, aD21;
                {
                    short8 A0 = Bf[(T0*4 + 0)*64 + L];
                    short8 A1 = Bf[(T1*4 + 0)*64 + L];
                    aH0  = __builtin_amdgcn_mfma_f32_16x16x32_bf16(A0, fh[0],  b2C4[T0*4 + q], 0, 0, 0);
                    aH1  = __builtin_amdgcn_mfma_f32_16x16x32_bf16(A1, fh[0],  b2C4[T1*4 + q], 0, 0, 0);
                    aD00 = __builtin_amdgcn_mfma_f32_16x16x32_bf16(A0, fd0[0], Z4, 0, 0, 0);
                    aD01 = __builtin_amdgcn_mfma_f32_16x16x32_bf16(A1, fd0[0], Z4, 0, 0, 0);
                    aD10 = __builtin_amdgcn_mfma_f32_16x16x32_bf16(A0, fd1[0], Z4, 0, 0, 0);
                    aD11 = __builtin_amdgcn_mfma_f32_16x16x32_bf16(A1, fd1[0], Z4, 0, 0, 0);
                    aD20 = __builtin_amdgcn_mfma_f32_16x16x32_bf16(A0, fd2[0], Z4, 0, 0, 0);
                    aD21 = __builtin_amdgcn_mfma_f32_16x16x32_bf16(A1, fd2[0], Z4, 0, 0, 0);
                }
                #pragma unroll
                for (int s = 1; s < 4; ++s) {
                    short8 A0 = Bf[(T0*4 + s)*64 + L];
                    short8 A1 = Bf[(T1*4 + s)*64 + L];
                    aH0  = __builtin_amdgcn_mfma_f32_16x16x32_bf16(A0, fh[s],  aH0,  0, 0, 0);
                    aH1  = __builtin_amdgcn_mfma_f32_16x16x32_bf16(A1, fh[s],  aH1,  0, 0, 0);
                    aD00 = __builtin_amdgcn_mfma_f32_16x16x32_bf16(A0, fd0[s], aD00, 0, 0, 0);
                    aD01 = __builtin_amdgcn_mfma_f32_16x16x32_bf16(A1, fd0[s], aD01, 0, 0, 0);
                    aD10 = __builtin_amdgcn_mfma_f32_16x16x32_bf16(A0, fd1[s], aD10, 0, 0, 0);
                    aD11 = __builtin_amdgcn_mfma_f32_16x16x32_bf16(A1, fd1[s], aD11, 0, 0, 0);
                    aD20 = __builtin_amdgcn_mfma_f32_16x16x32_bf16(A0, fd2[s], aD20, 0, 0, 0);
                    aD21 = __builtin_amdgcn_mfma_f32_16x16x32_bf16(A1, fd2[s], aD21, 0, 0, 0);
                }
                // post for this slice: h2/s2/dd -> e-frags -> 4 L3 MFMAs
                f32x2 h0 = tanh2(aH0.xy), h1 = tanh2(aH0.zw);
                f32x2 h2v = tanh2(aH1.xy), h3 = tanh2(aH1.zw);
                f32x2 s0 = fma2(-h0, h0, sp2(1.0f));
                f32x2 s1 = fma2(-h1, h1, sp2(1.0f));
                f32x2 s2v = fma2(-h2v, h2v, sp2(1.0f));
                f32x2 s3 = fma2(-h3, h3, sp2(1.0f));
                short8 eh = mk8(pkv(h0), pkv(h1), pkv(h2v), pkv(h3));
                short8 e0 = mk8(pkv(s0*aD00.xy), pkv(s1*aD00.zw), pkv(s2v*aD01.xy), pkv(s3*aD01.zw));
                short8 e1 = mk8(pkv(s0*aD10.xy), pkv(s1*aD10.zw), pkv(s2v*aD11.xy), pkv(s3*aD11.zw));
                short8 e2 = mk8(pkv(s0*aD20.xy), pkv(s1*aD20.zw), pkv(s2v*aD21.xy), pkv(s3*aD21.zw));
                const short8 WA = W3Af[qi*64 + L];
                V  = __builtin_amdgcn_mfma_f32_16x16x32_bf16(WA, eh, V,  0, 0, 0);
                J0 = __builtin_amdgcn_mfma_f32_16x16x32_bf16(WA, e0, J0, 0, 0, 0);
                J1 = __builtin_amdgcn_mfma_f32_16x16x32_bf16(WA, e1, J1, 0, 0, 0);
                J2 = __builtin_amdgcn_mfma_f32_16x16x32_bf16(WA, e2, J2, 0, 0, 0);
                __builtin_amdgcn_sched_barrier(0);
            }
            vx = __shfl(V[0], m, 64) + b30;
            vy = __shfl(V[1], m, 64) + b31;
            vz = __shfl(V[2], m, 64) + b32;
            // Jr stays LOCAL: point m's Jacobian rows live in its q==0 lane's
            // J0..J2 regs 0..2 (other q-lanes hold zero rows -> harmless D).
        }

        // def + state update. J{k}[o] = dJ_o/dx_k (valid on q==0; 0 elsewhere).
        {
            f32x2 ndp[3]; float nds[3];
            #pragma unroll
            for (int o = 0; o < 3; ++o) {
                f32x2 tp = J0[o] * Dp[0];
                tp = fma2(sp2(J1[o]), Dp[1], tp);
                tp = fma2(sp2(J2[o]), Dp[2], tp);
                ndp[o] = fma2(sp2(-dt_), tp, Dp[o]);
                float ts = J0[o]*Ds[0];
                ts = fmaf(J1[o], Ds[1], ts);
                ts = fmaf(J2[o], Ds[2], ts);
                nds[o] = fmaf(-dt_, ts, Ds[o]);
            }
            #pragma unroll
            for (int o = 0; o < 3; ++o) { Dp[o] = ndp[o]; Ds[o] = nds[o]; }
        }
        px_ = fmaf(-dt_, vx, px_);
        py_ = fmaf(-dt_, vy, py_);
        pz_ = fmaf(-dt_, vz, pz_);
        tc_  -= dt_;
        off_ -= dt_;
    }

    // ---- output: q==0 lane of each point writes xyz + deform
    if (q == 0) {
        out[p*3+0] = px_; out[p*3+1] = py_; out[p*3+2] = pz_;
        float* o9 = out + (size_t)N*3 + (size_t)p*9;
        #pragma unroll
        for (int o = 0; o < 3; ++o) {
            o9[o*3+0] = Dp[o][0];
            o9[o*3+1] = Dp[o][1];
            o9[o*3+2] = Ds[o];
        }
    }
}

extern "C" void kernel_launch(void* const* d_in, const int* in_sizes, int n_in,
                              void* d_out, int out_size, void* d_ws, size_t ws_size,
                              hipStream_t stream) {
    const float* code = (const float*)d_in[0];
    const float* pos  = (const float*)d_in[1];
    const float* t1   = (const float*)d_in[2];
    const float* t2   = (const float*)d_in[3];
    const float* W1   = (const float*)d_in[4];
    const float* b1   = (const float*)d_in[5];
    const float* W2   = (const float*)d_in[6];
    const float* b2   = (const float*)d_in[7];
    const float* W3   = (const float*)d_in[8];
    const float* b3   = (const float*)d_in[9];
    float* out = (float*)d_out;
    const int N = in_sizes[1] / 3;           // 131072
    const int blocks = N / PPB;              // 2048

    // R18 sort pre-pass (perf-only; output is permutation-invariant).
    const size_t need = 128 + (size_t)N * sizeof(int);
    int* perm = nullptr;
    if (d_ws && ws_size >= need) {
        unsigned* cnt = (unsigned*)d_ws;                 // [0..8] hist, [9..17] bases
        perm = (int*)((char*)d_ws + 128);
        const int pblocks = (N + 255) / 256;
        prep_zero<<<1, 64, 0, stream>>>(cnt);
        prep_hist<<<pblocks, 256, 0, stream>>>(t1, t2, cnt, N);
        prep_prefix<<<1, 64, 0, stream>>>(cnt);
        prep_scatter<<<pblocks, 256, 0, stream>>>(t1, t2, cnt, perm, N);
    }
    velwarp<<<blocks, 256, 0, stream>>>(code, pos, t1, t2, W1, b1, W2, b2, W3, b3, out, perm, N);
}

// Round 10
// 302.256 us; speedup vs baseline: 4.1712x; 4.1712x over previous
//
#include <hip/hip_runtime.h>
#include <hip/hip_bf16.h>

#define H 128
#define NSTEPS 8
#define DT_MAXF 0.125f
#define WAVES 4
#define PPW 16            // points per wave (one 16x16 MFMA N-tile)
#define PPB (WAVES*PPW)   // 64 points per block

typedef __attribute__((ext_vector_type(8))) short short8;   // 8 bf16 MFMA A/B frag
typedef __attribute__((ext_vector_type(4))) float floatx4;  // MFMA C/D frag
typedef __attribute__((ext_vector_type(2))) float f32x2;    // packed-FP32 pair (v_pk_*_f32)

__device__ __forceinline__ f32x2 sp2(float v) { return (f32x2){v, v}; }
__device__ __forceinline__ f32x2 fma2(f32x2 a, f32x2 b, f32x2 c) {
    return __builtin_elementwise_fma(a, b, c);              // -> v_pk_fma_f32
}
// tanh pair, merged-rcp form (R17): 1/(ea+1) = (eb+1)*rcp((ea+1)(eb+1)).
__device__ __forceinline__ f32x2 tanh2(f32x2 x) {
    f32x2 y = x * 2.8853900817779268f;
    f32x2 e; e[0] = __builtin_amdgcn_exp2f(y[0]); e[1] = __builtin_amdgcn_exp2f(y[1]);
    f32x2 ep = e + 1.0f;
    float rt = __builtin_amdgcn_rcpf(ep[0] * ep[1]);
    f32x2 eps = __builtin_shufflevector(ep, ep, 1, 0);
    f32x2 r = eps * sp2(rt);
    return fma2(sp2(-2.0f), r, sp2(1.0f));
}
__device__ __forceinline__ unsigned f2bf(float x) {           // fp32 -> bf16 bits, RNE
    unsigned u = __float_as_uint(x);
    return (u + 0x7FFFu + ((u >> 16) & 1u)) >> 16;
}
__device__ __forceinline__ unsigned pk2(float a, float b) {   // packed bf16 cvt
    union { __hip_bfloat162 h; unsigned u; } U;
    U.h = __float22bfloat162_rn(make_float2(a, b));
    return U.u;
}
__device__ __forceinline__ unsigned pkv(f32x2 v) { return pk2(v[0], v[1]); }
__device__ __forceinline__ short8 mk8(unsigned a, unsigned b, unsigned c, unsigned d) {
    union { unsigned u[4]; short8 s; } U;
    U.u[0] = a; U.u[1] = b; U.u[2] = c; U.u[3] = d; return U.s;
}
// xyzt B-frag, hi/lo split bf16. Lane q=0 carries hi+lo, q=1 carries hi, q>=2 zero.
__device__ __forceinline__ short8 xyzt_frag(float x, float y, float z, float t, int q) {
    unsigned hx = f2bf(x), hy = f2bf(y), hz = f2bf(z), ht = f2bf(t);
    float lx = x - __uint_as_float(hx << 16);
    float ly = y - __uint_as_float(hy << 16);
    float lz = z - __uint_as_float(hz << 16);
    float lt = t - __uint_as_float(ht << 16);
    unsigned w0 = hx | (hy << 16), w1 = hz | (ht << 16);
    unsigned w2 = pk2(lx, ly),     w3 = pk2(lz, lt);
    union { unsigned u[4]; short8 s; } F;
    F.u[0] = (q < 2)  ? w0 : 0u;
    F.u[1] = (q < 2)  ? w1 : 0u;
    F.u[2] = (q == 0) ? w2 : 0u;
    F.u[3] = (q == 0) ? w3 : 0u;
    return F.s;
}

// ---- R18/R19 pre-pass: counting-sort points by needed-step bucket ----
// b = ceil(|t1-t2|*8) in [0,8]. Sorted waves share a bucket -> the main
// kernel's wave-uniform break skips finished steps (exact no-ops, so output
// is BITWISE IDENTICAL for any permutation; sorting is perf-only).
// R19: R18's flat global atomics serialized on 9 cache lines (prep_hist
// 491us!). Standard two-level fix (Guideline 12): per-block LDS histogram,
// then <=9 global atomics PER BLOCK (4.6K total vs 131K).
__device__ __forceinline__ int step_bucket(float t1v, float t2v) {
    float off = fabsf(t1v - t2v);
    int b = (int)ceilf(off * 8.0f);
    return min(max(b, 0), 8);
}
__global__ void prep_zero(unsigned* cnt) {
    if (threadIdx.x < 18) cnt[threadIdx.x] = 0u;
}
__global__ void prep_hist(const float* __restrict__ t1g, const float* __restrict__ t2g,
                          unsigned* cnt, int N) {
    __shared__ unsigned h[9];
    if (threadIdx.x < 9) h[threadIdx.x] = 0u;
    __syncthreads();
    int i = blockIdx.x * 256 + threadIdx.x;
    if (i < N) atomicAdd(&h[step_bucket(t1g[i], t2g[i])], 1u);
    __syncthreads();
    if (threadIdx.x < 9 && h[threadIdx.x]) atomicAdd(&cnt[threadIdx.x], h[threadIdx.x]);
}
__global__ void prep_prefix(unsigned* cnt) {
    if (threadIdx.x == 0) {
        unsigned run = 0;
        for (int b = 0; b < 9; ++b) { unsigned c = cnt[b]; cnt[9 + b] = run; run += c; }
    }
}
__global__ void prep_scatter(const float* __restrict__ t1g, const float* __restrict__ t2g,
                             unsigned* cnt, int* __restrict__ perm, int N) {
    __shared__ unsigned h[9];     // block-local counts / rank allocator
    __shared__ unsigned base[9];  // global base reserved for this block
    if (threadIdx.x < 9) h[threadIdx.x] = 0u;
    __syncthreads();
    int i = blockIdx.x * 256 + threadIdx.x;
    int b = 0; unsigned r = 0;
    if (i < N) {
        b = step_bucket(t1g[i], t2g[i]);
        r = atomicAdd(&h[b], 1u);          // block-local rank within bucket
    }
    __syncthreads();
    if (threadIdx.x < 9 && h[threadIdx.x])
        base[threadIdx.x] = atomicAdd(&cnt[9 + threadIdx.x], h[threadIdx.x]);
    __syncthreads();
    if (i < N) perm[base[b] + r] = i;      // unique slot -> bitwise-safe perm
}

// R12: L1/L2/L3 on the MFMA pipe (pi-permuted k; zero cross-lane repack).
// R13-R16: occupancy arc NULL. R17: per-step work near-irreducible.
// R18: cut STEPS EXECUTED -- sort by needed-step bucket, wave-uniform break
//   when all 16 points done (exact no-ops after; bitwise-same output).
//   Validated on HW: velwarp dropped to ~270us, absmax exact. Pre-pass was
//   the regression (global-atomic serialization) -- fixed in R19 above.
__global__ __launch_bounds__(256, 2)
void velwarp(const float* __restrict__ code, const float* __restrict__ pos,
             const float* __restrict__ t1g, const float* __restrict__ t2g,
             const float* __restrict__ W1, const float* __restrict__ b1,
             const float* __restrict__ W2, const float* __restrict__ b2,
             const float* __restrict__ W3, const float* __restrict__ b3,
             float* __restrict__ out, const int* __restrict__ perm, int N)
{
    __shared__ __align__(16) uint4 WbufU[2048];   // 32KB: W1 fp32 staging (init) then W2 bf16 frags
    __shared__ __align__(16) uint4 W1AU[8*64];    // 8KB : layer-1 A-frags (xyzt rows, hi/lo split)
    __shared__ __align__(16) uint4 W3AU[4*64];    // 4KB : layer-3 A-frags (W3^T, pi-permuted)
    __shared__ __align__(16) floatx4 WdX4[32];    // W1[64][u] in C/D order (= row-linear)
    __shared__ __align__(16) floatx4 WdY4[32];    // W1[65][u]
    __shared__ __align__(16) floatx4 WdZ4[32];    // W1[66][u]
    __shared__ __align__(16) floatx4 b2C4[32];    // b2 in C/D order

    const int tid = threadIdx.x;
    const int L   = tid & 63;
    const int m   = L & 15;      // this lane's point (C/D col)
    const int q   = L >> 4;      // C/D row group = q*4+reg; B-frag k-quad
    const int pb  = blockIdx.x * PPB + (tid >> 6) * PPW;
    const int p   = perm ? perm[pb + m] : (pb + m);   // global point index

    // ---- stage W1 rows [0:64) as fp32 into Wbuf
    {
        const float4* s4 = (const float4*)W1;
        float4* d4 = (float4*)WbufU;
        #pragma unroll 4
        for (int i = tid; i < (64*H)/4; i += 256) d4[i] = s4[i];
    }
    // ---- layer-1 A-frags: tile t, lane l: row u = 16t+(l&15); hi/lo split
    for (int e = tid; e < 512; e += 256) {
        int t = e >> 6, l = e & 63;
        int u = t*16 + (l & 15), qq = l >> 4;
        unsigned hb[4], lb[4];
        #pragma unroll
        for (int c = 0; c < 4; ++c) {
            float wv = W1[(64 + c)*H + u];
            unsigned hh = f2bf(wv);
            float wl = wv - __uint_as_float(hh << 16);
            hb[c] = hh; lb[c] = f2bf(wl);
        }
        unsigned hi01 = hb[0] | (hb[1] << 16), hi23 = hb[2] | (hb[3] << 16);
        unsigned lo01 = lb[0] | (lb[1] << 16), lo23 = lb[2] | (lb[3] << 16);
        uint4 o;
        if (qq == 0)      o = make_uint4(hi01, hi23, hi01, hi23);
        else if (qq == 1) o = make_uint4(lo01, lo23, 0u, 0u);
        else              o = make_uint4(0u, 0u, 0u, 0u);
        W1AU[e] = o;
    }
    // ---- layer-3 A-frags: slice s, lane l: row a = l&15 (rows 3..15 zero)
    for (int e = tid; e < 256; e += 256) {
        int s = e >> 6, l = e & 63;
        int a = l & 15, qq = l >> 4;
        uint4 o = make_uint4(0u, 0u, 0u, 0u);
        if (a < 3) {
            int u0 = s*32 + qq*4, u1 = u0 + 16;
            o.x = f2bf(W3[(u0+0)*3+a]) | (f2bf(W3[(u0+1)*3+a]) << 16);
            o.y = f2bf(W3[(u0+2)*3+a]) | (f2bf(W3[(u0+3)*3+a]) << 16);
            o.z = f2bf(W3[(u1+0)*3+a]) | (f2bf(W3[(u1+1)*3+a]) << 16);
            o.w = f2bf(W3[(u1+2)*3+a]) | (f2bf(W3[(u1+3)*3+a]) << 16);
        }
        W3AU[e] = o;
    }
    if (tid < 32) {
        WdX4[tid] = ((const floatx4*)(W1 + (size_t)64*H))[tid];
        WdY4[tid] = ((const floatx4*)(W1 + (size_t)65*H))[tid];
        WdZ4[tid] = ((const floatx4*)(W1 + (size_t)66*H))[tid];
        b2C4[tid] = ((const floatx4*)b2)[tid];
    }
    __syncthreads();

    // ---- base1C[t] (fp32, C/D layout): u = 16t + 4q + reg
    floatx4 base1C[8];
    {
        #pragma unroll
        for (int t = 0; t < 8; ++t) base1C[t] = *(const floatx4*)&b1[t*16 + q*4];
        const float* Ws = (const float*)WbufU;
        const float* crow = code + (size_t)p * 64;
        for (int i = 0; i < 64; ++i) {
            f32x2 c = sp2(crow[i]);
            #pragma unroll
            for (int t = 0; t < 8; ++t) {
                floatx4 wq = *(const floatx4*)&Ws[i*H + t*16 + q*4];
                base1C[t].xy = fma2(c, wq.xy, base1C[t].xy);
                base1C[t].zw = fma2(c, wq.zw, base1C[t].zw);
            }
        }
    }
    __syncthreads();   // all lanes done reading W1 fp32 before repack

    // ---- pack W2 -> bf16 A-frags with pi-permuted k
    for (int ch = tid; ch < 2048; ch += 256) {
        int ln = ch & 63, ts = ch >> 6;
        int s = ts & 3, t = ts >> 2;
        int qq = ln >> 4, n = t*16 + (ln & 15);
        int u0 = s*32 + qq*4, u1 = u0 + 16;
        unsigned w0 = f2bf(W2[(u0+0)*H+n]) | (f2bf(W2[(u0+1)*H+n]) << 16);
        unsigned w1 = f2bf(W2[(u0+2)*H+n]) | (f2bf(W2[(u0+3)*H+n]) << 16);
        unsigned w2 = f2bf(W2[(u1+0)*H+n]) | (f2bf(W2[(u1+1)*H+n]) << 16);
        unsigned w3v = f2bf(W2[(u1+2)*H+n]) | (f2bf(W2[(u1+3)*H+n]) << 16);
        WbufU[ch] = make_uint4(w0, w1, w2, w3v);
    }

    // ---- per-lane point state
    float px_ = pos[p*3+0], py_ = pos[p*3+1], pz_ = pos[p*3+2];
    float tc_ = t1g[p];
    float off_ = tc_ - t2g[p];
    // deform D as 3 packed col-pairs + 3 scalars (cols 0,1 | col 2), row o
    f32x2 Dp[3]; float Ds[3];
    Dp[0] = (f32x2){1.f, 0.f}; Ds[0] = 0.f;
    Dp[1] = (f32x2){0.f, 1.f}; Ds[1] = 0.f;
    Dp[2] = (f32x2){0.f, 0.f}; Ds[2] = 1.f;
    const float b30 = b3[0], b31 = b3[1], b32 = b3[2];
    __syncthreads();

    const short8* Bf   = (const short8*)WbufU;
    const short8* W1Af = (const short8*)W1AU;
    const short8* W3Af = (const short8*)W3AU;
    const floatx4 Z4 = {0.f, 0.f, 0.f, 0.f};

    for (int step = 0; step < NSTEPS; ++step) {
        // R18: all remaining steps for this wave's 16 points are exact no-ops
        // (off_==0 -> dt_=0). Wave-uniform skip; bitwise-same output.
        if (!__any(off_ != 0.0f)) break;

        // ======== eval A: v(x,t) ========
        float vAx, vAy, vAz;
        {
            short8 xf = xyzt_frag(px_, py_, pz_, tc_, q);
            floatx4 z[8];
            #pragma unroll
            for (int t = 0; t < 8; ++t)
                z[t] = __builtin_amdgcn_mfma_f32_16x16x32_bf16(W1Af[t*64 + L], xf, base1C[t], 0, 0, 0);
            short8 fh[4];
            #pragma unroll
            for (int s = 0; s < 4; ++s) {
                f32x2 a0 = tanh2(z[2*s].xy),   a1 = tanh2(z[2*s].zw);
                f32x2 c0 = tanh2(z[2*s+1].xy), c1 = tanh2(z[2*s+1].zw);
                fh[s] = mk8(pkv(a0), pkv(a1), pkv(c0), pkv(c1));
            }
            __builtin_amdgcn_sched_barrier(0);
            // quarter qi covers tiles 2qi,2qi+1 == L3 slice qi
            floatx4 vacc = Z4;
            #pragma unroll
            for (int qi = 0; qi < 4; ++qi) {
                const int T0 = 2*qi, T1 = 2*qi + 1;
                floatx4 acc0 = __builtin_amdgcn_mfma_f32_16x16x32_bf16(
                    Bf[(T0*4 + 0)*64 + L], fh[0], b2C4[T0*4 + q], 0, 0, 0);
                floatx4 acc1 = __builtin_amdgcn_mfma_f32_16x16x32_bf16(
                    Bf[(T1*4 + 0)*64 + L], fh[0], b2C4[T1*4 + q], 0, 0, 0);
                #pragma unroll
                for (int s = 1; s < 4; ++s) {
                    acc0 = __builtin_amdgcn_mfma_f32_16x16x32_bf16(Bf[(T0*4 + s)*64 + L], fh[s], acc0, 0, 0, 0);
                    acc1 = __builtin_amdgcn_mfma_f32_16x16x32_bf16(Bf[(T1*4 + s)*64 + L], fh[s], acc1, 0, 0, 0);
                }
                f32x2 e00 = tanh2(acc0.xy), e01 = tanh2(acc0.zw);
                f32x2 e10 = tanh2(acc1.xy), e11 = tanh2(acc1.zw);
                short8 ef = mk8(pkv(e00), pkv(e01), pkv(e10), pkv(e11));
                vacc = __builtin_amdgcn_mfma_f32_16x16x32_bf16(W3Af[qi*64 + L], ef, vacc, 0, 0, 0);
                __builtin_amdgcn_sched_barrier(0);
            }
            vAx = __shfl(vacc[0], m, 64);
            vAy = __shfl(vacc[1], m, 64);
            vAz = __shfl(vacc[2], m, 64);
        }

        float dt_ = copysignf(fminf(fabsf(off_), DT_MAXF), off_);
        float hd = 0.5f * dt_;
        float mx = px_ - hd*(vAx + b30);
        float my = py_ - hd*(vAy + b31);
        float mz = pz_ - hd*(vAz + b32);
        float tm = tc_ - hd;

        // ======== eval B: v + Jacobian at midpoint ========
        float vx, vy, vz;
        floatx4 V = Z4, J0 = Z4, J1 = Z4, J2 = Z4;
        {
            short8 xf = xyzt_frag(mx, my, mz, tm, q);
            floatx4 z[8];
            #pragma unroll
            for (int t = 0; t < 8; ++t)
                z[t] = __builtin_amdgcn_mfma_f32_16x16x32_bf16(W1Af[t*64 + L], xf, base1C[t], 0, 0, 0);
            short8 fh[4], fd0[4], fd1[4], fd2[4];
            #pragma unroll
            for (int s = 0; s < 4; ++s) {
                unsigned uh[4], u0[4], u1[4], u2[4];
                #pragma unroll
                for (int hf = 0; hf < 2; ++hf) {
                    int t = 2*s + hf;
                    f32x2 h0 = tanh2(z[t].xy), h1 = tanh2(z[t].zw);
                    f32x2 s0 = fma2(-h0, h0, sp2(1.0f));
                    f32x2 s1 = fma2(-h1, h1, sp2(1.0f));
                    floatx4 wx = WdX4[t*4 + q], wy = WdY4[t*4 + q], wz = WdZ4[t*4 + q];
                    uh[2*hf+0] = pkv(h0);         uh[2*hf+1] = pkv(h1);
                    u0[2*hf+0] = pkv(s0 * wx.xy); u0[2*hf+1] = pkv(s1 * wx.zw);
                    u1[2*hf+0] = pkv(s0 * wy.xy); u1[2*hf+1] = pkv(s1 * wy.zw);
                    u2[2*hf+0] = pkv(s0 * wz.xy); u2[2*hf+1] = pkv(s1 * wz.zw);
                }
                fh[s]  = mk8(uh[0], uh[1], uh[2], uh[3]);
                fd0[s] = mk8(u0[0], u0[1], u0[2], u0[3]);
                fd1[s] = mk8(u1[0], u1[1], u1[2], u1[3]);
                fd2[s] = mk8(u2[0], u2[1], u2[2], u2[3]);
            }
            __builtin_amdgcn_sched_barrier(0);
            // quarter qi = one L3 slice: tiles 2qi,2qi+1, all 4 chains, post,
            // 4 L3 MFMAs.
            #pragma unroll
            for (int qi = 0; qi < 4; ++qi) {
                const int T0 = 2*qi, T1 = 2*qi + 1;
                floatx4 aH0, aH1, aD00, aD01, aD10, aD11, aD20, aD21;
                {
                    short8 A0 = Bf[(T0*4 + 0)*64 + L];
                    short8 A1 = Bf[(T1*4 + 0)*64 + L];
                    aH0  = __builtin_amdgcn_mfma_f32_16x16x32_bf16(A0, fh[0],  b2C4[T0*4 + q], 0, 0, 0);
                    aH1  = __builtin_amdgcn_mfma_f32_16x16x32_bf16(A1, fh[0],  b2C4[T1*4 + q], 0, 0, 0);
                    aD00 = __builtin_amdgcn_mfma_f32_16x16x32_bf16(A0, fd0[0], Z4, 0, 0, 0);
                    aD01 = __builtin_amdgcn_mfma_f32_16x16x32_bf16(A1, fd0[0], Z4, 0, 0, 0);
                    aD10 = __builtin_amdgcn_mfma_f32_16x16x32_bf16(A0, fd1[0], Z4, 0, 0, 0);
                    aD11 = __builtin_amdgcn_mfma_f32_16x16x32_bf16(A1, fd1[0], Z4, 0, 0, 0);
                    aD20 = __builtin_amdgcn_mfma_f32_16x16x32_bf16(A0, fd2[0], Z4, 0, 0, 0);
                    aD21 = __builtin_amdgcn_mfma_f32_16x16x32_bf16(A1, fd2[0], Z4, 0, 0, 0);
                }
                #pragma unroll
                for (int s = 1; s < 4; ++s) {
                    short8 A0 = Bf[(T0*4 + s)*64 + L];
                    short8 A1 = Bf[(T1*4 + s)*64 + L];
                    aH0  = __builtin_amdgcn_mfma_f32_16x16x32_bf16(A0, fh[s],  aH0,  0, 0, 0);
                    aH1  = __builtin_amdgcn_mfma_f32_16x16x32_bf16(A1, fh[s],  aH1,  0, 0, 0);
                    aD00 = __builtin_amdgcn_mfma_f32_16x16x32_bf16(A0, fd0[s], aD00, 0, 0, 0);
                    aD01 = __builtin_amdgcn_mfma_f32_16x16x32_bf16(A1, fd0[s], aD01, 0, 0, 0);
                    aD10 = __builtin_amdgcn_mfma_f32_16x16x32_bf16(A0, fd1[s], aD10, 0, 0, 0);
                    aD11 = __builtin_amdgcn_mfma_f32_16x16x32_bf16(A1, fd1[s], aD11, 0, 0, 0);
                    aD20 = __builtin_amdgcn_mfma_f32_16x16x32_bf16(A0, fd2[s], aD20, 0, 0, 0);
                    aD21 = __builtin_amdgcn_mfma_f32_16x16x32_bf16(A1, fd2[s], aD21, 0, 0, 0);
                }
                // post for this slice: h2/s2/dd -> e-frags -> 4 L3 MFMAs
                f32x2 h0 = tanh2(aH0.xy), h1 = tanh2(aH0.zw);
                f32x2 h2v = tanh2(aH1.xy), h3 = tanh2(aH1.zw);
                f32x2 s0 = fma2(-h0, h0, sp2(1.0f));
                f32x2 s1 = fma2(-h1, h1, sp2(1.0f));
                f32x2 s2v = fma2(-h2v, h2v, sp2(1.0f));
                f32x2 s3 = fma2(-h3, h3, sp2(1.0f));
                short8 eh = mk8(pkv(h0), pkv(h1), pkv(h2v), pkv(h3));
                short8 e0 = mk8(pkv(s0*aD00.xy), pkv(s1*aD00.zw), pkv(s2v*aD01.xy), pkv(s3*aD01.zw));
                short8 e1 = mk8(pkv(s0*aD10.xy), pkv(s1*aD10.zw), pkv(s2v*aD11.xy), pkv(s3*aD11.zw));
                short8 e2 = mk8(pkv(s0*aD20.xy), pkv(s1*aD20.zw), pkv(s2v*aD21.xy), pkv(s3*aD21.zw));
                const short8 WA = W3Af[qi*64 + L];
                V  = __builtin_amdgcn_mfma_f32_16x16x32_bf16(WA, eh, V,  0, 0, 0);
                J0 = __builtin_amdgcn_mfma_f32_16x16x32_bf16(WA, e0, J0, 0, 0, 0);
                J1 = __builtin_amdgcn_mfma_f32_16x16x32_bf16(WA, e1, J1, 0, 0, 0);
                J2 = __builtin_amdgcn_mfma_f32_16x16x32_bf16(WA, e2, J2, 0, 0, 0);
                __builtin_amdgcn_sched_barrier(0);
            }
            vx = __shfl(V[0], m, 64) + b30;
            vy = __shfl(V[1], m, 64) + b31;
            vz = __shfl(V[2], m, 64) + b32;
            // Jr stays LOCAL: point m's Jacobian rows live in its q==0 lane's
            // J0..J2 regs 0..2 (other q-lanes hold zero rows -> harmless D).
        }

        // def + state update. J{k}[o] = dJ_o/dx_k (valid on q==0; 0 elsewhere).
        {
            f32x2 ndp[3]; float nds[3];
            #pragma unroll
            for (int o = 0; o < 3; ++o) {
                f32x2 tp = J0[o] * Dp[0];
                tp = fma2(sp2(J1[o]), Dp[1], tp);
                tp = fma2(sp2(J2[o]), Dp[2], tp);
                ndp[o] = fma2(sp2(-dt_), tp, Dp[o]);
                float ts = J0[o]*Ds[0];
                ts = fmaf(J1[o], Ds[1], ts);
                ts = fmaf(J2[o], Ds[2], ts);
                nds[o] = fmaf(-dt_, ts, Ds[o]);
            }
            #pragma unroll
            for (int o = 0; o < 3; ++o) { Dp[o] = ndp[o]; Ds[o] = nds[o]; }
        }
        px_ = fmaf(-dt_, vx, px_);
        py_ = fmaf(-dt_, vy, py_);
        pz_ = fmaf(-dt_, vz, pz_);
        tc_  -= dt_;
        off_ -= dt_;
    }

    // ---- output: q==0 lane of each point writes xyz + deform
    if (q == 0) {
        out[p*3+0] = px_; out[p*3+1] = py_; out[p*3+2] = pz_;
        float* o9 = out + (size_t)N*3 + (size_t)p*9;
        #pragma unroll
        for (int o = 0; o < 3; ++o) {
            o9[o*3+0] = Dp[o][0];
            o9[o*3+1] = Dp[o][1];
            o9[o*3+2] = Ds[o];
        }
    }
}

extern "C" void kernel_launch(void* const* d_in, const int* in_sizes, int n_in,
                              void* d_out, int out_size, void* d_ws, size_t ws_size,
                              hipStream_t stream) {
    const float* code = (const float*)d_in[0];
    const float* pos  = (const float*)d_in[1];
    const float* t1   = (const float*)d_in[2];
    const float* t2   = (const float*)d_in[3];
    const float* W1   = (const float*)d_in[4];
    const float* b1   = (const float*)d_in[5];
    const float* W2   = (const float*)d_in[6];
    const float* b2   = (const float*)d_in[7];
    const float* W3   = (const float*)d_in[8];
    const float* b3   = (const float*)d_in[9];
    float* out = (float*)d_out;
    const int N = in_sizes[1] / 3;           // 131072
    const int blocks = N / PPB;              // 2048

    // R18/R19 sort pre-pass (perf-only; output is permutation-invariant).
    const size_t need = 128 + (size_t)N * sizeof(int);
    int* perm = nullptr;
    if (d_ws && ws_size >= need) {
        unsigned* cnt = (unsigned*)d_ws;                 // [0..8] hist, [9..17] bases
        perm = (int*)((char*)d_ws + 128);
        const int pblocks = (N + 255) / 256;
        prep_zero<<<1, 64, 0, stream>>>(cnt);
        prep_hist<<<pblocks, 256, 0, stream>>>(t1, t2, cnt, N);
        prep_prefix<<<1, 64, 0, stream>>>(cnt);
        prep_scatter<<<pblocks, 256, 0, stream>>>(t1, t2, cnt, perm, N);
    }
    velwarp<<<blocks, 256, 0, stream>>>(code, pos, t1, t2, W1, b1, W2, b2, W3, b3, out, perm, N);
}

// Round 11
// 278.965 us; speedup vs baseline: 4.5195x; 1.0835x over previous
//
#include <hip/hip_runtime.h>
#include <hip/hip_bf16.h>

#define H 128
#define NSTEPS 8
#define DT_MAXF 0.125f
#define WAVES 4
#define PPW 16            // points per wave (one 16x16 MFMA N-tile)
#define PPB (WAVES*PPW)   // 64 points per block

typedef __attribute__((ext_vector_type(8))) short short8;   // 8 bf16 MFMA A/B frag
typedef __attribute__((ext_vector_type(4))) float floatx4;  // MFMA C/D frag
typedef __attribute__((ext_vector_type(2))) float f32x2;    // packed-FP32 pair (v_pk_*_f32)

__device__ __forceinline__ f32x2 sp2(float v) { return (f32x2){v, v}; }
__device__ __forceinline__ f32x2 fma2(f32x2 a, f32x2 b, f32x2 c) {
    return __builtin_elementwise_fma(a, b, c);              // -> v_pk_fma_f32
}
// tanh pair, merged-rcp form (R17): 1/(ea+1) = (eb+1)*rcp((ea+1)(eb+1)).
__device__ __forceinline__ f32x2 tanh2(f32x2 x) {
    f32x2 y = x * 2.8853900817779268f;
    f32x2 e; e[0] = __builtin_amdgcn_exp2f(y[0]); e[1] = __builtin_amdgcn_exp2f(y[1]);
    f32x2 ep = e + 1.0f;
    float rt = __builtin_amdgcn_rcpf(ep[0] * ep[1]);
    f32x2 eps = __builtin_shufflevector(ep, ep, 1, 0);
    f32x2 r = eps * sp2(rt);
    return fma2(sp2(-2.0f), r, sp2(1.0f));
}
__device__ __forceinline__ unsigned f2bf(float x) {           // fp32 -> bf16 bits, RNE
    unsigned u = __float_as_uint(x);
    return (u + 0x7FFFu + ((u >> 16) & 1u)) >> 16;
}
__device__ __forceinline__ unsigned pk2(float a, float b) {   // packed bf16 cvt
    union { __hip_bfloat162 h; unsigned u; } U;
    U.h = __float22bfloat162_rn(make_float2(a, b));
    return U.u;
}
__device__ __forceinline__ unsigned pkv(f32x2 v) { return pk2(v[0], v[1]); }
__device__ __forceinline__ short8 mk8(unsigned a, unsigned b, unsigned c, unsigned d) {
    union { unsigned u[4]; short8 s; } U;
    U.u[0] = a; U.u[1] = b; U.u[2] = c; U.u[3] = d; return U.s;
}
// xyzt B-frag, hi/lo split bf16. Lane q=0 carries hi+lo, q=1 carries hi, q>=2 zero.
__device__ __forceinline__ short8 xyzt_frag(float x, float y, float z, float t, int q) {
    unsigned hx = f2bf(x), hy = f2bf(y), hz = f2bf(z), ht = f2bf(t);
    float lx = x - __uint_as_float(hx << 16);
    float ly = y - __uint_as_float(hy << 16);
    float lz = z - __uint_as_float(hz << 16);
    float lt = t - __uint_as_float(ht << 16);
    unsigned w0 = hx | (hy << 16), w1 = hz | (ht << 16);
    unsigned w2 = pk2(lx, ly),     w3 = pk2(lz, lt);
    union { unsigned u[4]; short8 s; } F;
    F.u[0] = (q < 2)  ? w0 : 0u;
    F.u[1] = (q < 2)  ? w1 : 0u;
    F.u[2] = (q == 0) ? w2 : 0u;
    F.u[3] = (q == 0) ? w3 : 0u;
    return F.s;
}

// ---- R18/R19 pre-pass: counting-sort points by needed-step bucket ----
// b = ceil(|t1-t2|*8) in [0,8]. Sorted waves share a bucket -> the main
// kernel's wave-uniform break skips finished steps (exact no-ops, so output
// is BITWISE IDENTICAL for any permutation; sorting is perf-only).
// R19: two-level histogram (LDS then <=9 global atomics/block).
// R20: prefix DESCENDING -> longest-running blocks launch first (LPT
// scheduling, better tail packing); prep_zero replaced by hipMemsetAsync.
__device__ __forceinline__ int step_bucket(float t1v, float t2v) {
    float off = fabsf(t1v - t2v);
    int b = (int)ceilf(off * 8.0f);
    return min(max(b, 0), 8);
}
__global__ void prep_hist(const float* __restrict__ t1g, const float* __restrict__ t2g,
                          unsigned* cnt, int N) {
    __shared__ unsigned h[9];
    if (threadIdx.x < 9) h[threadIdx.x] = 0u;
    __syncthreads();
    int i = blockIdx.x * 256 + threadIdx.x;
    if (i < N) atomicAdd(&h[step_bucket(t1g[i], t2g[i])], 1u);
    __syncthreads();
    if (threadIdx.x < 9 && h[threadIdx.x]) atomicAdd(&cnt[threadIdx.x], h[threadIdx.x]);
}
__global__ void prep_prefix(unsigned* cnt) {
    if (threadIdx.x == 0) {
        unsigned run = 0;
        for (int b = 8; b >= 0; --b) { unsigned c = cnt[b]; cnt[9 + b] = run; run += c; }
    }
}
__global__ void prep_scatter(const float* __restrict__ t1g, const float* __restrict__ t2g,
                             unsigned* cnt, int* __restrict__ perm, int N) {
    __shared__ unsigned h[9];     // block-local counts / rank allocator
    __shared__ unsigned base[9];  // global base reserved for this block
    if (threadIdx.x < 9) h[threadIdx.x] = 0u;
    __syncthreads();
    int i = blockIdx.x * 256 + threadIdx.x;
    int b = 0; unsigned r = 0;
    if (i < N) {
        b = step_bucket(t1g[i], t2g[i]);
        r = atomicAdd(&h[b], 1u);          // block-local rank within bucket
    }
    __syncthreads();
    if (threadIdx.x < 9 && h[threadIdx.x])
        base[threadIdx.x] = atomicAdd(&cnt[9 + threadIdx.x], h[threadIdx.x]);
    __syncthreads();
    if (i < N) perm[base[b] + r] = i;      // unique slot -> bitwise-safe perm
}

// R12: L1/L2/L3 on the MFMA pipe (pi-permuted k; zero cross-lane repack).
// R18/R19: sorted early-exit, validated (velwarp 374 -> 241us, absmax exact).
// R20: base1C (code.W1[:64], K=64 contraction) moved to MFMA too -- the
//   64-iter fp32 loop was 512 ds_read_b128 + 1024 v_pk_fma PER LANE of
//   pure init, no longer amortized now that avg steps = 4.5. hi/lo split,
//   3 chains (wh.ch + wh.cl + wl.ch; cl.wl ~2^-18 dropped) = 48 chained
//   MFMAs. W1[:64] packed in-kernel to hi/lo frags in the same 32KB Wbuf
//   slot (overwritten by W2 frags after, as before). Accumulation order
//   changes -> few-ulp fp32 wobble, absorbed by downstream bf16 rounding.
__global__ __launch_bounds__(256, 2)
void velwarp(const float* __restrict__ code, const float* __restrict__ pos,
             const float* __restrict__ t1g, const float* __restrict__ t2g,
             const float* __restrict__ W1, const float* __restrict__ b1,
             const float* __restrict__ W2, const float* __restrict__ b2,
             const float* __restrict__ W3, const float* __restrict__ b3,
             float* __restrict__ out, const int* __restrict__ perm, int N)
{
    __shared__ __align__(16) uint4 WbufU[2048];   // 32KB: W1 hi/lo frags (init) then W2 bf16 frags
    __shared__ __align__(16) uint4 W1AU[8*64];    // 8KB : layer-1 A-frags (xyzt rows, hi/lo split)
    __shared__ __align__(16) uint4 W3AU[4*64];    // 4KB : layer-3 A-frags (W3^T, pi-permuted)
    __shared__ __align__(16) floatx4 WdX4[32];    // W1[64][u] in C/D order (= row-linear)
    __shared__ __align__(16) floatx4 WdY4[32];    // W1[65][u]
    __shared__ __align__(16) floatx4 WdZ4[32];    // W1[66][u]
    __shared__ __align__(16) floatx4 b2C4[32];    // b2 in C/D order

    const int tid = threadIdx.x;
    const int L   = tid & 63;
    const int m   = L & 15;      // this lane's point (C/D col)
    const int q   = L >> 4;      // C/D row group = q*4+reg; B-frag k-quad
    const int pb  = blockIdx.x * PPB + (tid >> 6) * PPW;
    const int p   = perm ? perm[pb + m] : (pb + m);   // global point index

    // ---- pack W1 rows [0:64) as hi/lo bf16 A-frags into Wbuf (for base1C
    // MFMA). Layout [t][c][term][64] uint4; lane (qq,mm): row u=16t+mm,
    // k-slots g = 32c + {qq*4+0..3, 16+qq*4+0..3} (pi convention).
    for (int e = tid; e < 1024; e += 256) {
        int t = e >> 7, rem = e & 127;
        int c = rem >> 6, l = rem & 63;
        int qq = l >> 4, mm = l & 15;
        int u = t*16 + mm;
        int g0 = c*32 + qq*4, g1 = g0 + 16;
        unsigned hh[8]; float lo[8];
        #pragma unroll
        for (int j = 0; j < 4; ++j) {
            float w0 = W1[(g0+j)*H + u];
            float w1 = W1[(g1+j)*H + u];
            hh[j]   = f2bf(w0); lo[j]   = w0 - __uint_as_float(hh[j]   << 16);
            hh[4+j] = f2bf(w1); lo[4+j] = w1 - __uint_as_float(hh[4+j] << 16);
        }
        WbufU[((t*2+c)*2+0)*64 + l] = make_uint4(hh[0]|(hh[1]<<16), hh[2]|(hh[3]<<16),
                                                 hh[4]|(hh[5]<<16), hh[6]|(hh[7]<<16));
        WbufU[((t*2+c)*2+1)*64 + l] = make_uint4(pk2(lo[0],lo[1]), pk2(lo[2],lo[3]),
                                                 pk2(lo[4],lo[5]), pk2(lo[6],lo[7]));
    }
    // ---- layer-1 A-frags: tile t, lane l: row u = 16t+(l&15); hi/lo split
    for (int e = tid; e < 512; e += 256) {
        int t = e >> 6, l = e & 63;
        int u = t*16 + (l & 15), qq = l >> 4;
        unsigned hb[4], lb[4];
        #pragma unroll
        for (int c = 0; c < 4; ++c) {
            float wv = W1[(64 + c)*H + u];
            unsigned hh = f2bf(wv);
            float wl = wv - __uint_as_float(hh << 16);
            hb[c] = hh; lb[c] = f2bf(wl);
        }
        unsigned hi01 = hb[0] | (hb[1] << 16), hi23 = hb[2] | (hb[3] << 16);
        unsigned lo01 = lb[0] | (lb[1] << 16), lo23 = lb[2] | (lb[3] << 16);
        uint4 o;
        if (qq == 0)      o = make_uint4(hi01, hi23, hi01, hi23);
        else if (qq == 1) o = make_uint4(lo01, lo23, 0u, 0u);
        else              o = make_uint4(0u, 0u, 0u, 0u);
        W1AU[e] = o;
    }
    // ---- layer-3 A-frags: slice s, lane l: row a = l&15 (rows 3..15 zero)
    for (int e = tid; e < 256; e += 256) {
        int s = e >> 6, l = e & 63;
        int a = l & 15, qq = l >> 4;
        uint4 o = make_uint4(0u, 0u, 0u, 0u);
        if (a < 3) {
            int u0 = s*32 + qq*4, u1 = u0 + 16;
            o.x = f2bf(W3[(u0+0)*3+a]) | (f2bf(W3[(u0+1)*3+a]) << 16);
            o.y = f2bf(W3[(u0+2)*3+a]) | (f2bf(W3[(u0+3)*3+a]) << 16);
            o.z = f2bf(W3[(u1+0)*3+a]) | (f2bf(W3[(u1+1)*3+a]) << 16);
            o.w = f2bf(W3[(u1+2)*3+a]) | (f2bf(W3[(u1+3)*3+a]) << 16);
        }
        W3AU[e] = o;
    }
    if (tid < 32) {
        WdX4[tid] = ((const floatx4*)(W1 + (size_t)64*H))[tid];
        WdY4[tid] = ((const floatx4*)(W1 + (size_t)65*H))[tid];
        WdZ4[tid] = ((const floatx4*)(W1 + (size_t)66*H))[tid];
        b2C4[tid] = ((const floatx4*)b2)[tid];
    }
    __syncthreads();

    // ---- base1C via MFMA (R20): 3-chain hi/lo, 6 chained MFMAs per tile
    floatx4 base1C[8];
    {
        const float4* crow4 = (const float4*)(code + (size_t)p * 64);
        short8 Bh[2], Bl[2];
        #pragma unroll
        for (int c = 0; c < 2; ++c) {
            float4 a = crow4[c*8 + q];        // k = 32c + q*4 + 0..3
            float4 b = crow4[c*8 + 4 + q];    // k = 32c + 16 + q*4 + 0..3
            unsigned h0 = f2bf(a.x), h1 = f2bf(a.y), h2 = f2bf(a.z), h3 = f2bf(a.w);
            unsigned g0 = f2bf(b.x), g1 = f2bf(b.y), g2 = f2bf(b.z), g3 = f2bf(b.w);
            float l0 = a.x - __uint_as_float(h0<<16), l1 = a.y - __uint_as_float(h1<<16);
            float l2 = a.z - __uint_as_float(h2<<16), l3 = a.w - __uint_as_float(h3<<16);
            float m0 = b.x - __uint_as_float(g0<<16), m1 = b.y - __uint_as_float(g1<<16);
            float m2 = b.z - __uint_as_float(g2<<16), m3 = b.w - __uint_as_float(g3<<16);
            Bh[c] = mk8(h0|(h1<<16), h2|(h3<<16), g0|(g1<<16), g2|(g3<<16));
            Bl[c] = mk8(pk2(l0,l1), pk2(l2,l3), pk2(m0,m1), pk2(m2,m3));
        }
        const short8* Wb = (const short8*)WbufU;   // [t][c][term][64]
        #pragma unroll
        for (int t = 0; t < 8; ++t) {
            floatx4 z = *(const floatx4*)&b1[t*16 + q*4];
            short8 Wh0 = Wb[((t*2+0)*2+0)*64 + L];
            short8 Wh1 = Wb[((t*2+1)*2+0)*64 + L];
            short8 Wl0 = Wb[((t*2+0)*2+1)*64 + L];
            short8 Wl1 = Wb[((t*2+1)*2+1)*64 + L];
            z = __builtin_amdgcn_mfma_f32_16x16x32_bf16(Wh0, Bh[0], z, 0, 0, 0);
            z = __builtin_amdgcn_mfma_f32_16x16x32_bf16(Wh1, Bh[1], z, 0, 0, 0);
            z = __builtin_amdgcn_mfma_f32_16x16x32_bf16(Wh0, Bl[0], z, 0, 0, 0);
            z = __builtin_amdgcn_mfma_f32_16x16x32_bf16(Wh1, Bl[1], z, 0, 0, 0);
            z = __builtin_amdgcn_mfma_f32_16x16x32_bf16(Wl0, Bh[0], z, 0, 0, 0);
            z = __builtin_amdgcn_mfma_f32_16x16x32_bf16(Wl1, Bh[1], z, 0, 0, 0);
            base1C[t] = z;
        }
    }
    __syncthreads();   // all lanes done reading W1b frags before W2 repack

    // ---- pack W2 -> bf16 A-frags with pi-permuted k
    for (int ch = tid; ch < 2048; ch += 256) {
        int ln = ch & 63, ts = ch >> 6;
        int s = ts & 3, t = ts >> 2;
        int qq = ln >> 4, n = t*16 + (ln & 15);
        int u0 = s*32 + qq*4, u1 = u0 + 16;
        unsigned w0 = f2bf(W2[(u0+0)*H+n]) | (f2bf(W2[(u0+1)*H+n]) << 16);
        unsigned w1 = f2bf(W2[(u0+2)*H+n]) | (f2bf(W2[(u0+3)*H+n]) << 16);
        unsigned w2 = f2bf(W2[(u1+0)*H+n]) | (f2bf(W2[(u1+1)*H+n]) << 16);
        unsigned w3v = f2bf(W2[(u1+2)*H+n]) | (f2bf(W2[(u1+3)*H+n]) << 16);
        WbufU[ch] = make_uint4(w0, w1, w2, w3v);
    }

    // ---- per-lane point state
    float px_ = pos[p*3+0], py_ = pos[p*3+1], pz_ = pos[p*3+2];
    float tc_ = t1g[p];
    float off_ = tc_ - t2g[p];
    // deform D as 3 packed col-pairs + 3 scalars (cols 0,1 | col 2), row o
    f32x2 Dp[3]; float Ds[3];
    Dp[0] = (f32x2){1.f, 0.f}; Ds[0] = 0.f;
    Dp[1] = (f32x2){0.f, 1.f}; Ds[1] = 0.f;
    Dp[2] = (f32x2){0.f, 0.f}; Ds[2] = 1.f;
    const float b30 = b3[0], b31 = b3[1], b32 = b3[2];
    __syncthreads();

    const short8* Bf   = (const short8*)WbufU;
    const short8* W1Af = (const short8*)W1AU;
    const short8* W3Af = (const short8*)W3AU;
    const floatx4 Z4 = {0.f, 0.f, 0.f, 0.f};

    for (int step = 0; step < NSTEPS; ++step) {
        // R18: all remaining steps for this wave's 16 points are exact no-ops
        // (off_==0 -> dt_=0). Wave-uniform skip; bitwise-same output.
        if (!__any(off_ != 0.0f)) break;

        // ======== eval A: v(x,t) ========
        float vAx, vAy, vAz;
        {
            short8 xf = xyzt_frag(px_, py_, pz_, tc_, q);
            floatx4 z[8];
            #pragma unroll
            for (int t = 0; t < 8; ++t)
                z[t] = __builtin_amdgcn_mfma_f32_16x16x32_bf16(W1Af[t*64 + L], xf, base1C[t], 0, 0, 0);
            short8 fh[4];
            #pragma unroll
            for (int s = 0; s < 4; ++s) {
                f32x2 a0 = tanh2(z[2*s].xy),   a1 = tanh2(z[2*s].zw);
                f32x2 c0 = tanh2(z[2*s+1].xy), c1 = tanh2(z[2*s+1].zw);
                fh[s] = mk8(pkv(a0), pkv(a1), pkv(c0), pkv(c1));
            }
            __builtin_amdgcn_sched_barrier(0);
            // quarter qi covers tiles 2qi,2qi+1 == L3 slice qi
            floatx4 vacc = Z4;
            #pragma unroll
            for (int qi = 0; qi < 4; ++qi) {
                const int T0 = 2*qi, T1 = 2*qi + 1;
                floatx4 acc0 = __builtin_amdgcn_mfma_f32_16x16x32_bf16(
                    Bf[(T0*4 + 0)*64 + L], fh[0], b2C4[T0*4 + q], 0, 0, 0);
                floatx4 acc1 = __builtin_amdgcn_mfma_f32_16x16x32_bf16(
                    Bf[(T1*4 + 0)*64 + L], fh[0], b2C4[T1*4 + q], 0, 0, 0);
                #pragma unroll
                for (int s = 1; s < 4; ++s) {
                    acc0 = __builtin_amdgcn_mfma_f32_16x16x32_bf16(Bf[(T0*4 + s)*64 + L], fh[s], acc0, 0, 0, 0);
                    acc1 = __builtin_amdgcn_mfma_f32_16x16x32_bf16(Bf[(T1*4 + s)*64 + L], fh[s], acc1, 0, 0, 0);
                }
                f32x2 e00 = tanh2(acc0.xy), e01 = tanh2(acc0.zw);
                f32x2 e10 = tanh2(acc1.xy), e11 = tanh2(acc1.zw);
                short8 ef = mk8(pkv(e00), pkv(e01), pkv(e10), pkv(e11));
                vacc = __builtin_amdgcn_mfma_f32_16x16x32_bf16(W3Af[qi*64 + L], ef, vacc, 0, 0, 0);
                __builtin_amdgcn_sched_barrier(0);
            }
            vAx = __shfl(vacc[0], m, 64);
            vAy = __shfl(vacc[1], m, 64);
            vAz = __shfl(vacc[2], m, 64);
        }

        float dt_ = copysignf(fminf(fabsf(off_), DT_MAXF), off_);
        float hd = 0.5f * dt_;
        float mx = px_ - hd*(vAx + b30);
        float my = py_ - hd*(vAy + b31);
        float mz = pz_ - hd*(vAz + b32);
        float tm = tc_ - hd;

        // ======== eval B: v + Jacobian at midpoint ========
        float vx, vy, vz;
        floatx4 V = Z4, J0 = Z4, J1 = Z4, J2 = Z4;
        {
            short8 xf = xyzt_frag(mx, my, mz, tm, q);
            floatx4 z[8];
            #pragma unroll
            for (int t = 0; t < 8; ++t)
                z[t] = __builtin_amdgcn_mfma_f32_16x16x32_bf16(W1Af[t*64 + L], xf, base1C[t], 0, 0, 0);
            short8 fh[4], fd0[4], fd1[4], fd2[4];
            #pragma unroll
            for (int s = 0; s < 4; ++s) {
                unsigned uh[4], u0[4], u1[4], u2[4];
                #pragma unroll
                for (int hf = 0; hf < 2; ++hf) {
                    int t = 2*s + hf;
                    f32x2 h0 = tanh2(z[t].xy), h1 = tanh2(z[t].zw);
                    f32x2 s0 = fma2(-h0, h0, sp2(1.0f));
                    f32x2 s1 = fma2(-h1, h1, sp2(1.0f));
                    floatx4 wx = WdX4[t*4 + q], wy = WdY4[t*4 + q], wz = WdZ4[t*4 + q];
                    uh[2*hf+0] = pkv(h0);         uh[2*hf+1] = pkv(h1);
                    u0[2*hf+0] = pkv(s0 * wx.xy); u0[2*hf+1] = pkv(s1 * wx.zw);
                    u1[2*hf+0] = pkv(s0 * wy.xy); u1[2*hf+1] = pkv(s1 * wy.zw);
                    u2[2*hf+0] = pkv(s0 * wz.xy); u2[2*hf+1] = pkv(s1 * wz.zw);
                }
                fh[s]  = mk8(uh[0], uh[1], uh[2], uh[3]);
                fd0[s] = mk8(u0[0], u0[1], u0[2], u0[3]);
                fd1[s] = mk8(u1[0], u1[1], u1[2], u1[3]);
                fd2[s] = mk8(u2[0], u2[1], u2[2], u2[3]);
            }
            __builtin_amdgcn_sched_barrier(0);
            // quarter qi = one L3 slice: tiles 2qi,2qi+1, all 4 chains, post,
            // 4 L3 MFMAs.
            #pragma unroll
            for (int qi = 0; qi < 4; ++qi) {
                const int T0 = 2*qi, T1 = 2*qi + 1;
                floatx4 aH0, aH1, aD00, aD01, aD10, aD11, aD20, aD21;
                {
                    short8 A0 = Bf[(T0*4 + 0)*64 + L];
                    short8 A1 = Bf[(T1*4 + 0)*64 + L];
                    aH0  = __builtin_amdgcn_mfma_f32_16x16x32_bf16(A0, fh[0],  b2C4[T0*4 + q], 0, 0, 0);
                    aH1  = __builtin_amdgcn_mfma_f32_16x16x32_bf16(A1, fh[0],  b2C4[T1*4 + q], 0, 0, 0);
                    aD00 = __builtin_amdgcn_mfma_f32_16x16x32_bf16(A0, fd0[0], Z4, 0, 0, 0);
                    aD01 = __builtin_amdgcn_mfma_f32_16x16x32_bf16(A1, fd0[0], Z4, 0, 0, 0);
                    aD10 = __builtin_amdgcn_mfma_f32_16x16x32_bf16(A0, fd1[0], Z4, 0, 0, 0);
                    aD11 = __builtin_amdgcn_mfma_f32_16x16x32_bf16(A1, fd1[0], Z4, 0, 0, 0);
                    aD20 = __builtin_amdgcn_mfma_f32_16x16x32_bf16(A0, fd2[0], Z4, 0, 0, 0);
                    aD21 = __builtin_amdgcn_mfma_f32_16x16x32_bf16(A1, fd2[0], Z4, 0, 0, 0);
                }
                #pragma unroll
                for (int s = 1; s < 4; ++s) {
                    short8 A0 = Bf[(T0*4 + s)*64 + L];
                    short8 A1 = Bf[(T1*4 + s)*64 + L];
                    aH0  = __builtin_amdgcn_mfma_f32_16x16x32_bf16(A0, fh[s],  aH0,  0, 0, 0);
                    aH1  = __builtin_amdgcn_mfma_f32_16x16x32_bf16(A1, fh[s],  aH1,  0, 0, 0);
                    aD00 = __builtin_amdgcn_mfma_f32_16x16x32_bf16(A0, fd0[s], aD00, 0, 0, 0);
                    aD01 = __builtin_amdgcn_mfma_f32_16x16x32_bf16(A1, fd0[s], aD01, 0, 0, 0);
                    aD10 = __builtin_amdgcn_mfma_f32_16x16x32_bf16(A0, fd1[s], aD10, 0, 0, 0);
                    aD11 = __builtin_amdgcn_mfma_f32_16x16x32_bf16(A1, fd1[s], aD11, 0, 0, 0);
                    aD20 = __builtin_amdgcn_mfma_f32_16x16x32_bf16(A0, fd2[s], aD20, 0, 0, 0);
                    aD21 = __builtin_amdgcn_mfma_f32_16x16x32_bf16(A1, fd2[s], aD21, 0, 0, 0);
                }
                // post for this slice: h2/s2/dd -> e-frags -> 4 L3 MFMAs
                f32x2 h0 = tanh2(aH0.xy), h1 = tanh2(aH0.zw);
                f32x2 h2v = tanh2(aH1.xy), h3 = tanh2(aH1.zw);
                f32x2 s0 = fma2(-h0, h0, sp2(1.0f));
                f32x2 s1 = fma2(-h1, h1, sp2(1.0f));
                f32x2 s2v = fma2(-h2v, h2v, sp2(1.0f));
                f32x2 s3 = fma2(-h3, h3, sp2(1.0f));
                short8 eh = mk8(pkv(h0), pkv(h1), pkv(h2v), pkv(h3));
                short8 e0 = mk8(pkv(s0*aD00.xy), pkv(s1*aD00.zw), pkv(s2v*aD01.xy), pkv(s3*aD01.zw));
                short8 e1 = mk8(pkv(s0*aD10.xy), pkv(s1*aD10.zw), pkv(s2v*aD11.xy), pkv(s3*aD11.zw));
                short8 e2 = mk8(pkv(s0*aD20.xy), pkv(s1*aD20.zw), pkv(s2v*aD21.xy), pkv(s3*aD21.zw));
                const short8 WA = W3Af[qi*64 + L];
                V  = __builtin_amdgcn_mfma_f32_16x16x32_bf16(WA, eh, V,  0, 0, 0);
                J0 = __builtin_amdgcn_mfma_f32_16x16x32_bf16(WA, e0, J0, 0, 0, 0);
                J1 = __builtin_amdgcn_mfma_f32_16x16x32_bf16(WA, e1, J1, 0, 0, 0);
                J2 = __builtin_amdgcn_mfma_f32_16x16x32_bf16(WA, e2, J2, 0, 0, 0);
                __builtin_amdgcn_sched_barrier(0);
            }
            vx = __shfl(V[0], m, 64) + b30;
            vy = __shfl(V[1], m, 64) + b31;
            vz = __shfl(V[2], m, 64) + b32;
            // Jr stays LOCAL: point m's Jacobian rows live in its q==0 lane's
            // J0..J2 regs 0..2 (other q-lanes hold zero rows -> harmless D).
        }

        // def + state update. J{k}[o] = dJ_o/dx_k (valid on q==0; 0 elsewhere).
        {
            f32x2 ndp[3]; float nds[3];
            #pragma unroll
            for (int o = 0; o < 3; ++o) {
                f32x2 tp = J0[o] * Dp[0];
                tp = fma2(sp2(J1[o]), Dp[1], tp);
                tp = fma2(sp2(J2[o]), Dp[2], tp);
                ndp[o] = fma2(sp2(-dt_), tp, Dp[o]);
                float ts = J0[o]*Ds[0];
                ts = fmaf(J1[o], Ds[1], ts);
                ts = fmaf(J2[o], Ds[2], ts);
                nds[o] = fmaf(-dt_, ts, Ds[o]);
            }
            #pragma unroll
            for (int o = 0; o < 3; ++o) { Dp[o] = ndp[o]; Ds[o] = nds[o]; }
        }
        px_ = fmaf(-dt_, vx, px_);
        py_ = fmaf(-dt_, vy, py_);
        pz_ = fmaf(-dt_, vz, pz_);
        tc_  -= dt_;
        off_ -= dt_;
    }

    // ---- output: q==0 lane of each point writes xyz + deform
    if (q == 0) {
        out[p*3+0] = px_; out[p*3+1] = py_; out[p*3+2] = pz_;
        float* o9 = out + (size_t)N*3 + (size_t)p*9;
        #pragma unroll
        for (int o = 0; o < 3; ++o) {
            o9[o*3+0] = Dp[o][0];
            o9[o*3+1] = Dp[o][1];
            o9[o*3+2] = Ds[o];
        }
    }
}

extern "C" void kernel_launch(void* const* d_in, const int* in_sizes, int n_in,
                              void* d_out, int out_size, void* d_ws, size_t ws_size,
                              hipStream_t stream) {
    const float* code = (const float*)d_in[0];
    const float* pos  = (const float*)d_in[1];
    const float* t1   = (const float*)d_in[2];
    const float* t2   = (const float*)d_in[3];
    const float* W1   = (const float*)d_in[4];
    const float* b1   = (const float*)d_in[5];
    const float* W2   = (const float*)d_in[6];
    const float* b2   = (const float*)d_in[7];
    const float* W3   = (const float*)d_in[8];
    const float* b3   = (const float*)d_in[9];
    float* out = (float*)d_out;
    const int N = in_sizes[1] / 3;           // 131072
    const int blocks = N / PPB;              // 2048

    // R18-R20 sort pre-pass (perf-only; output is permutation-invariant).
    const size_t need = 128 + (size_t)N * sizeof(int);
    int* perm = nullptr;
    if (d_ws && ws_size >= need) {
        unsigned* cnt = (unsigned*)d_ws;                 // [0..8] hist, [9..17] bases
        perm = (int*)((char*)d_ws + 128);
        const int pblocks = (N + 255) / 256;
        hipMemsetAsync(d_ws, 0, 128, stream);
        prep_hist<<<pblocks, 256, 0, stream>>>(t1, t2, cnt, N);
        prep_prefix<<<1, 64, 0, stream>>>(cnt);
        prep_scatter<<<pblocks, 256, 0, stream>>>(t1, t2, cnt, perm, N);
    }
    velwarp<<<blocks, 256, 0, stream>>>(code, pos, t1, t2, W1, b1, W2, b2, W3, b3, out, perm, N);
}

// Round 12
// 272.803 us; speedup vs baseline: 4.6216x; 1.0226x over previous
//
#include <hip/hip_runtime.h>
#include <hip/hip_bf16.h>

#define H 128
#define NSTEPS 8
#define DT_MAXF 0.125f
#define WAVES 4
#define PPW 16            // points per wave (one 16x16 MFMA N-tile)
#define PPB (WAVES*PPW)   // 64 points per block
#define WPACK_U4 4992     // packed-weights size in uint4 (79872 B)

typedef __attribute__((ext_vector_type(8))) short short8;   // 8 bf16 MFMA A/B frag
typedef __attribute__((ext_vector_type(4))) float floatx4;  // MFMA C/D frag
typedef __attribute__((ext_vector_type(2))) float f32x2;    // packed-FP32 pair (v_pk_*_f32)

__device__ __forceinline__ f32x2 sp2(float v) { return (f32x2){v, v}; }
__device__ __forceinline__ f32x2 fma2(f32x2 a, f32x2 b, f32x2 c) {
    return __builtin_elementwise_fma(a, b, c);              // -> v_pk_fma_f32
}
// tanh pair, merged-rcp form (R17): 1/(ea+1) = (eb+1)*rcp((ea+1)(eb+1)).
__device__ __forceinline__ f32x2 tanh2(f32x2 x) {
    f32x2 y = x * 2.8853900817779268f;
    f32x2 e; e[0] = __builtin_amdgcn_exp2f(y[0]); e[1] = __builtin_amdgcn_exp2f(y[1]);
    f32x2 ep = e + 1.0f;
    float rt = __builtin_amdgcn_rcpf(ep[0] * ep[1]);
    f32x2 eps = __builtin_shufflevector(ep, ep, 1, 0);
    f32x2 r = eps * sp2(rt);
    return fma2(sp2(-2.0f), r, sp2(1.0f));
}
__device__ __forceinline__ unsigned f2bf(float x) {           // fp32 -> bf16 bits, RNE
    unsigned u = __float_as_uint(x);
    return (u + 0x7FFFu + ((u >> 16) & 1u)) >> 16;
}
__device__ __forceinline__ unsigned pk2(float a, float b) {   // packed bf16 cvt
    union { __hip_bfloat162 h; unsigned u; } U;
    U.h = __float22bfloat162_rn(make_float2(a, b));
    return U.u;
}
__device__ __forceinline__ unsigned pkv(f32x2 v) { return pk2(v[0], v[1]); }
__device__ __forceinline__ short8 mk8(unsigned a, unsigned b, unsigned c, unsigned d) {
    union { unsigned u[4]; short8 s; } U;
    U.u[0] = a; U.u[1] = b; U.u[2] = c; U.u[3] = d; return U.s;
}
// xyzt B-frag, hi/lo split bf16. Lane q=0 carries hi+lo, q=1 carries hi, q>=2 zero.
__device__ __forceinline__ short8 xyzt_frag(float x, float y, float z, float t, int q) {
    unsigned hx = f2bf(x), hy = f2bf(y), hz = f2bf(z), ht = f2bf(t);
    float lx = x - __uint_as_float(hx << 16);
    float ly = y - __uint_as_float(hy << 16);
    float lz = z - __uint_as_float(hz << 16);
    float lt = t - __uint_as_float(ht << 16);
    unsigned w0 = hx | (hy << 16), w1 = hz | (ht << 16);
    unsigned w2 = pk2(lx, ly),     w3 = pk2(lz, lt);
    union { unsigned u[4]; short8 s; } F;
    F.u[0] = (q < 2)  ? w0 : 0u;
    F.u[1] = (q < 2)  ? w1 : 0u;
    F.u[2] = (q == 0) ? w2 : 0u;
    F.u[3] = (q == 0) ? w3 : 0u;
    return F.s;
}

// ---- R18/R19 pre-pass: counting-sort points by needed-step bucket ----
// b = ceil(|t1-t2|*8) in [0,8]. Sorted waves share a bucket -> the main
// kernel's wave-uniform break skips finished steps (exact no-ops; output
// is BITWISE IDENTICAL for any permutation; sorting is perf-only).
// R19: two-level histogram. R20: descending prefix (LPT scheduling).
__device__ __forceinline__ int step_bucket(float t1v, float t2v) {
    float off = fabsf(t1v - t2v);
    int b = (int)ceilf(off * 8.0f);
    return min(max(b, 0), 8);
}
__global__ void prep_hist(const float* __restrict__ t1g, const float* __restrict__ t2g,
                          unsigned* cnt, int N) {
    __shared__ unsigned h[9];
    if (threadIdx.x < 9) h[threadIdx.x] = 0u;
    __syncthreads();
    int i = blockIdx.x * 256 + threadIdx.x;
    if (i < N) atomicAdd(&h[step_bucket(t1g[i], t2g[i])], 1u);
    __syncthreads();
    if (threadIdx.x < 9 && h[threadIdx.x]) atomicAdd(&cnt[threadIdx.x], h[threadIdx.x]);
}
__global__ void prep_prefix(unsigned* cnt) {
    if (threadIdx.x == 0) {
        unsigned run = 0;
        for (int b = 8; b >= 0; --b) { unsigned c = cnt[b]; cnt[9 + b] = run; run += c; }
    }
}
__global__ void prep_scatter(const float* __restrict__ t1g, const float* __restrict__ t2g,
                             unsigned* cnt, int* __restrict__ perm, int N) {
    __shared__ unsigned h[9];     // block-local counts / rank allocator
    __shared__ unsigned base[9];  // global base reserved for this block
    if (threadIdx.x < 9) h[threadIdx.x] = 0u;
    __syncthreads();
    int i = blockIdx.x * 256 + threadIdx.x;
    int b = 0; unsigned r = 0;
    if (i < N) {
        b = step_bucket(t1g[i], t2g[i]);
        r = atomicAdd(&h[b], 1u);          // block-local rank within bucket
    }
    __syncthreads();
    if (threadIdx.x < 9 && h[threadIdx.x])
        base[threadIdx.x] = atomicAdd(&cnt[9 + threadIdx.x], h[threadIdx.x]);
    __syncthreads();
    if (i < N) perm[base[b] + r] = i;      // unique slot -> bitwise-safe perm
}

// ---- R21: pack all weight fragments ONCE into d_ws ----
// Every velwarp block previously re-ran ~16K f2bf conversions producing
// byte-identical LDS content. Pack once here (same index math, global
// dest); velwarp init becomes a linear 44KB L2-resident copy.
// Layout (uint4 offsets): [0,2048) W1b frags; [2048,4096) W2 frags;
// [4096,4608) W1A; [4608,4864) W3A; [4864,4992) WdX|WdY|WdZ|b2C (32 each).
__global__ void prep_pack(const float* __restrict__ W1, const float* __restrict__ W2,
                          const float* __restrict__ W3, const float* __restrict__ b2,
                          uint4* __restrict__ wp) {
    const int gid = blockIdx.x * 256 + threadIdx.x;
    const int stride = gridDim.x * 256;
    // W1b hi/lo frags (for base1C MFMA): [t][c][term][64]
    for (int e = gid; e < 1024; e += stride) {
        int t = e >> 7, rem = e & 127;
        int c = rem >> 6, l = rem & 63;
        int qq = l >> 4, mm = l & 15;
        int u = t*16 + mm;
        int g0 = c*32 + qq*4, g1 = g0 + 16;
        unsigned hh[8]; float lo[8];
        #pragma unroll
        for (int j = 0; j < 4; ++j) {
            float w0 = W1[(g0+j)*H + u];
            float w1 = W1[(g1+j)*H + u];
            hh[j]   = f2bf(w0); lo[j]   = w0 - __uint_as_float(hh[j]   << 16);
            hh[4+j] = f2bf(w1); lo[4+j] = w1 - __uint_as_float(hh[4+j] << 16);
        }
        wp[((t*2+c)*2+0)*64 + l] = make_uint4(hh[0]|(hh[1]<<16), hh[2]|(hh[3]<<16),
                                              hh[4]|(hh[5]<<16), hh[6]|(hh[7]<<16));
        wp[((t*2+c)*2+1)*64 + l] = make_uint4(pk2(lo[0],lo[1]), pk2(lo[2],lo[3]),
                                              pk2(lo[4],lo[5]), pk2(lo[6],lo[7]));
    }
    // W2 -> bf16 A-frags, pi-permuted k
    for (int ch = gid; ch < 2048; ch += stride) {
        int ln = ch & 63, ts = ch >> 6;
        int s = ts & 3, t = ts >> 2;
        int qq = ln >> 4, n = t*16 + (ln & 15);
        int u0 = s*32 + qq*4, u1 = u0 + 16;
        unsigned w0 = f2bf(W2[(u0+0)*H+n]) | (f2bf(W2[(u0+1)*H+n]) << 16);
        unsigned w1 = f2bf(W2[(u0+2)*H+n]) | (f2bf(W2[(u0+3)*H+n]) << 16);
        unsigned w2 = f2bf(W2[(u1+0)*H+n]) | (f2bf(W2[(u1+1)*H+n]) << 16);
        unsigned w3v = f2bf(W2[(u1+2)*H+n]) | (f2bf(W2[(u1+3)*H+n]) << 16);
        wp[2048 + ch] = make_uint4(w0, w1, w2, w3v);
    }
    // layer-1 A-frags (xyzt rows, hi/lo split)
    for (int e = gid; e < 512; e += stride) {
        int t = e >> 6, l = e & 63;
        int u = t*16 + (l & 15), qq = l >> 4;
        unsigned hb[4], lb[4];
        #pragma unroll
        for (int c = 0; c < 4; ++c) {
            float wv = W1[(64 + c)*H + u];
            unsigned hh = f2bf(wv);
            float wl = wv - __uint_as_float(hh << 16);
            hb[c] = hh; lb[c] = f2bf(wl);
        }
        unsigned hi01 = hb[0] | (hb[1] << 16), hi23 = hb[2] | (hb[3] << 16);
        unsigned lo01 = lb[0] | (lb[1] << 16), lo23 = lb[2] | (lb[3] << 16);
        uint4 o;
        if (qq == 0)      o = make_uint4(hi01, hi23, hi01, hi23);
        else if (qq == 1) o = make_uint4(lo01, lo23, 0u, 0u);
        else              o = make_uint4(0u, 0u, 0u, 0u);
        wp[4096 + e] = o;
    }
    // layer-3 A-frags (W3^T, pi-permuted; rows 3..15 zero)
    for (int e = gid; e < 256; e += stride) {
        int s = e >> 6, l = e & 63;
        int a = l & 15, qq = l >> 4;
        uint4 o = make_uint4(0u, 0u, 0u, 0u);
        if (a < 3) {
            int u0 = s*32 + qq*4, u1 = u0 + 16;
            o.x = f2bf(W3[(u0+0)*3+a]) | (f2bf(W3[(u0+1)*3+a]) << 16);
            o.y = f2bf(W3[(u0+2)*3+a]) | (f2bf(W3[(u0+3)*3+a]) << 16);
            o.z = f2bf(W3[(u1+0)*3+a]) | (f2bf(W3[(u1+1)*3+a]) << 16);
            o.w = f2bf(W3[(u1+2)*3+a]) | (f2bf(W3[(u1+3)*3+a]) << 16);
        }
        wp[4608 + e] = o;
    }
    // WdX/WdY/WdZ (W1 rows 64..66, row-linear) and b2 (C/D order == linear)
    for (int i = gid; i < 128; i += stride) {
        int sec = i >> 5, k = i & 31;
        float4 v = (sec < 3) ? ((const float4*)(W1 + (size_t)(64+sec)*H))[k]
                             : ((const float4*)b2)[k];
        wp[4864 + i] = *(const uint4*)&v;
    }
}

// R12: L1/L2/L3 on the MFMA pipe (pi-permuted k; zero cross-lane repack).
// R18/R19: sorted early-exit (velwarp 374 -> 241us). R20: base1C via MFMA
// (241 -> 210). R21: weights packed once in prep_pack; init is now a linear
// 44KB copy (bit-identical LDS content). In-kernel pack kept as fallback
// when d_ws is too small (wpack == nullptr).
__global__ __launch_bounds__(256, 2)
void velwarp(const float* __restrict__ code, const float* __restrict__ pos,
             const float* __restrict__ t1g, const float* __restrict__ t2g,
             const float* __restrict__ W1, const float* __restrict__ b1,
             const float* __restrict__ W2, const float* __restrict__ b2,
             const float* __restrict__ W3, const float* __restrict__ b3,
             float* __restrict__ out, const int* __restrict__ perm,
             const uint4* __restrict__ wpack, int N)
{
    __shared__ __align__(16) uint4 WbufU[2048];   // 32KB: W1 hi/lo frags (init) then W2 bf16 frags
    __shared__ __align__(16) uint4 W1AU[8*64];    // 8KB : layer-1 A-frags (xyzt rows, hi/lo split)
    __shared__ __align__(16) uint4 W3AU[4*64];    // 4KB : layer-3 A-frags (W3^T, pi-permuted)
    __shared__ __align__(16) floatx4 WdX4[32];    // W1[64][u] in C/D order (= row-linear)
    __shared__ __align__(16) floatx4 WdY4[32];    // W1[65][u]
    __shared__ __align__(16) floatx4 WdZ4[32];    // W1[66][u]
    __shared__ __align__(16) floatx4 b2C4[32];    // b2 in C/D order

    const int tid = threadIdx.x;
    const int L   = tid & 63;
    const int m   = L & 15;      // this lane's point (C/D col)
    const int q   = L >> 4;      // C/D row group = q*4+reg; B-frag k-quad
    const int pb  = blockIdx.x * PPB + (tid >> 6) * PPW;
    const int p   = perm ? perm[pb + m] : (pb + m);   // global point index

    if (wpack) {
        // ---- R21 fast path: linear copy of pre-packed frags
        #pragma unroll 4
        for (int i = tid; i < 2048; i += 256) WbufU[i] = wpack[i];          // W1b frags
        #pragma unroll 2
        for (int i = tid; i < 512; i += 256) W1AU[i] = wpack[4096 + i];
        W3AU[tid < 256 ? tid : 0] = wpack[4608 + (tid < 256 ? tid : 0)];
        if (tid < 128) {
            int sec = tid >> 5, k = tid & 31;
            uint4 v = wpack[4864 + tid];
            floatx4 f = *(const floatx4*)&v;
            if (sec == 0)      WdX4[k] = f;
            else if (sec == 1) WdY4[k] = f;
            else if (sec == 2) WdZ4[k] = f;
            else               b2C4[k] = f;
        }
    } else {
        // ---- fallback: in-kernel pack (identical math to prep_pack)
        for (int e = tid; e < 1024; e += 256) {
            int t = e >> 7, rem = e & 127;
            int c = rem >> 6, l = rem & 63;
            int qq = l >> 4, mm = l & 15;
            int u = t*16 + mm;
            int g0 = c*32 + qq*4, g1 = g0 + 16;
            unsigned hh[8]; float lo[8];
            #pragma unroll
            for (int j = 0; j < 4; ++j) {
                float w0 = W1[(g0+j)*H + u];
                float w1 = W1[(g1+j)*H + u];
                hh[j]   = f2bf(w0); lo[j]   = w0 - __uint_as_float(hh[j]   << 16);
                hh[4+j] = f2bf(w1); lo[4+j] = w1 - __uint_as_float(hh[4+j] << 16);
            }
            WbufU[((t*2+c)*2+0)*64 + l] = make_uint4(hh[0]|(hh[1]<<16), hh[2]|(hh[3]<<16),
                                                     hh[4]|(hh[5]<<16), hh[6]|(hh[7]<<16));
            WbufU[((t*2+c)*2+1)*64 + l] = make_uint4(pk2(lo[0],lo[1]), pk2(lo[2],lo[3]),
                                                     pk2(lo[4],lo[5]), pk2(lo[6],lo[7]));
        }
        for (int e = tid; e < 512; e += 256) {
            int t = e >> 6, l = e & 63;
            int u = t*16 + (l & 15), qq = l >> 4;
            unsigned hb[4], lb[4];
            #pragma unroll
            for (int c = 0; c < 4; ++c) {
                float wv = W1[(64 + c)*H + u];
                unsigned hh = f2bf(wv);
                float wl = wv - __uint_as_float(hh << 16);
                hb[c] = hh; lb[c] = f2bf(wl);
            }
            unsigned hi01 = hb[0] | (hb[1] << 16), hi23 = hb[2] | (hb[3] << 16);
            unsigned lo01 = lb[0] | (lb[1] << 16), lo23 = lb[2] | (lb[3] << 16);
            uint4 o;
            if (qq == 0)      o = make_uint4(hi01, hi23, hi01, hi23);
            else if (qq == 1) o = make_uint4(lo01, lo23, 0u, 0u);
            else              o = make_uint4(0u, 0u, 0u, 0u);
            W1AU[e] = o;
        }
        for (int e = tid; e < 256; e += 256) {
            int s = e >> 6, l = e & 63;
            int a = l & 15, qq = l >> 4;
            uint4 o = make_uint4(0u, 0u, 0u, 0u);
            if (a < 3) {
                int u0 = s*32 + qq*4, u1 = u0 + 16;
                o.x = f2bf(W3[(u0+0)*3+a]) | (f2bf(W3[(u0+1)*3+a]) << 16);
                o.y = f2bf(W3[(u0+2)*3+a]) | (f2bf(W3[(u0+3)*3+a]) << 16);
                o.z = f2bf(W3[(u1+0)*3+a]) | (f2bf(W3[(u1+1)*3+a]) << 16);
                o.w = f2bf(W3[(u1+2)*3+a]) | (f2bf(W3[(u1+3)*3+a]) << 16);
            }
            W3AU[e] = o;
        }
        if (tid < 32) {
            WdX4[tid] = ((const floatx4*)(W1 + (size_t)64*H))[tid];
            WdY4[tid] = ((const floatx4*)(W1 + (size_t)65*H))[tid];
            WdZ4[tid] = ((const floatx4*)(W1 + (size_t)66*H))[tid];
            b2C4[tid] = ((const floatx4*)b2)[tid];
        }
    }
    __syncthreads();

    // ---- base1C via MFMA (R20): 3-chain hi/lo, 6 chained MFMAs per tile
    floatx4 base1C[8];
    {
        const float4* crow4 = (const float4*)(code + (size_t)p * 64);
        short8 Bh[2], Bl[2];
        #pragma unroll
        for (int c = 0; c < 2; ++c) {
            float4 a = crow4[c*8 + q];        // k = 32c + q*4 + 0..3
            float4 b = crow4[c*8 + 4 + q];    // k = 32c + 16 + q*4 + 0..3
            unsigned h0 = f2bf(a.x), h1 = f2bf(a.y), h2 = f2bf(a.z), h3 = f2bf(a.w);
            unsigned g0 = f2bf(b.x), g1 = f2bf(b.y), g2 = f2bf(b.z), g3 = f2bf(b.w);
            float l0 = a.x - __uint_as_float(h0<<16), l1 = a.y - __uint_as_float(h1<<16);
            float l2 = a.z - __uint_as_float(h2<<16), l3 = a.w - __uint_as_float(h3<<16);
            float m0 = b.x - __uint_as_float(g0<<16), m1 = b.y - __uint_as_float(g1<<16);
            float m2 = b.z - __uint_as_float(g2<<16), m3 = b.w - __uint_as_float(g3<<16);
            Bh[c] = mk8(h0|(h1<<16), h2|(h3<<16), g0|(g1<<16), g2|(g3<<16));
            Bl[c] = mk8(pk2(l0,l1), pk2(l2,l3), pk2(m0,m1), pk2(m2,m3));
        }
        const short8* Wb = (const short8*)WbufU;   // [t][c][term][64]
        #pragma unroll
        for (int t = 0; t < 8; ++t) {
            floatx4 z = *(const floatx4*)&b1[t*16 + q*4];
            short8 Wh0 = Wb[((t*2+0)*2+0)*64 + L];
            short8 Wh1 = Wb[((t*2+1)*2+0)*64 + L];
            short8 Wl0 = Wb[((t*2+0)*2+1)*64 + L];
            short8 Wl1 = Wb[((t*2+1)*2+1)*64 + L];
            z = __builtin_amdgcn_mfma_f32_16x16x32_bf16(Wh0, Bh[0], z, 0, 0, 0);
            z = __builtin_amdgcn_mfma_f32_16x16x32_bf16(Wh1, Bh[1], z, 0, 0, 0);
            z = __builtin_amdgcn_mfma_f32_16x16x32_bf16(Wh0, Bl[0], z, 0, 0, 0);
            z = __builtin_amdgcn_mfma_f32_16x16x32_bf16(Wh1, Bl[1], z, 0, 0, 0);
            z = __builtin_amdgcn_mfma_f32_16x16x32_bf16(Wl0, Bh[0], z, 0, 0, 0);
            z = __builtin_amdgcn_mfma_f32_16x16x32_bf16(Wl1, Bh[1], z, 0, 0, 0);
            base1C[t] = z;
        }
    }
    __syncthreads();   // all lanes done reading W1b frags before W2 overwrite

    if (wpack) {
        #pragma unroll 4
        for (int i = tid; i < 2048; i += 256) WbufU[i] = wpack[2048 + i];   // W2 frags
    } else {
        for (int ch = tid; ch < 2048; ch += 256) {
            int ln = ch & 63, ts = ch >> 6;
            int s = ts & 3, t = ts >> 2;
            int qq = ln >> 4, n = t*16 + (ln & 15);
            int u0 = s*32 + qq*4, u1 = u0 + 16;
            unsigned w0 = f2bf(W2[(u0+0)*H+n]) | (f2bf(W2[(u0+1)*H+n]) << 16);
            unsigned w1 = f2bf(W2[(u0+2)*H+n]) | (f2bf(W2[(u0+3)*H+n]) << 16);
            unsigned w2 = f2bf(W2[(u1+0)*H+n]) | (f2bf(W2[(u1+1)*H+n]) << 16);
            unsigned w3v = f2bf(W2[(u1+2)*H+n]) | (f2bf(W2[(u1+3)*H+n]) << 16);
            WbufU[ch] = make_uint4(w0, w1, w2, w3v);
        }
    }

    // ---- per-lane point state
    float px_ = pos[p*3+0], py_ = pos[p*3+1], pz_ = pos[p*3+2];
    float tc_ = t1g[p];
    float off_ = tc_ - t2g[p];
    // deform D as 3 packed col-pairs + 3 scalars (cols 0,1 | col 2), row o
    f32x2 Dp[3]; float Ds[3];
    Dp[0] = (f32x2){1.f, 0.f}; Ds[0] = 0.f;
    Dp[1] = (f32x2){0.f, 1.f}; Ds[1] = 0.f;
    Dp[2] = (f32x2){0.f, 0.f}; Ds[2] = 1.f;
    const float b30 = b3[0], b31 = b3[1], b32 = b3[2];
    __syncthreads();

    const short8* Bf   = (const short8*)WbufU;
    const short8* W1Af = (const short8*)W1AU;
    const short8* W3Af = (const short8*)W3AU;
    const floatx4 Z4 = {0.f, 0.f, 0.f, 0.f};

    for (int step = 0; step < NSTEPS; ++step) {
        // R18: all remaining steps for this wave's 16 points are exact no-ops
        // (off_==0 -> dt_=0). Wave-uniform skip; bitwise-same output.
        if (!__any(off_ != 0.0f)) break;

        // ======== eval A: v(x,t) ========
        float vAx, vAy, vAz;
        {
            short8 xf = xyzt_frag(px_, py_, pz_, tc_, q);
            floatx4 z[8];
            #pragma unroll
            for (int t = 0; t < 8; ++t)
                z[t] = __builtin_amdgcn_mfma_f32_16x16x32_bf16(W1Af[t*64 + L], xf, base1C[t], 0, 0, 0);
            short8 fh[4];
            #pragma unroll
            for (int s = 0; s < 4; ++s) {
                f32x2 a0 = tanh2(z[2*s].xy),   a1 = tanh2(z[2*s].zw);
                f32x2 c0 = tanh2(z[2*s+1].xy), c1 = tanh2(z[2*s+1].zw);
                fh[s] = mk8(pkv(a0), pkv(a1), pkv(c0), pkv(c1));
            }
            __builtin_amdgcn_sched_barrier(0);
            // quarter qi covers tiles 2qi,2qi+1 == L3 slice qi
            floatx4 vacc = Z4;
            #pragma unroll
            for (int qi = 0; qi < 4; ++qi) {
                const int T0 = 2*qi, T1 = 2*qi + 1;
                floatx4 acc0 = __builtin_amdgcn_mfma_f32_16x16x32_bf16(
                    Bf[(T0*4 + 0)*64 + L], fh[0], b2C4[T0*4 + q], 0, 0, 0);
                floatx4 acc1 = __builtin_amdgcn_mfma_f32_16x16x32_bf16(
                    Bf[(T1*4 + 0)*64 + L], fh[0], b2C4[T1*4 + q], 0, 0, 0);
                #pragma unroll
                for (int s = 1; s < 4; ++s) {
                    acc0 = __builtin_amdgcn_mfma_f32_16x16x32_bf16(Bf[(T0*4 + s)*64 + L], fh[s], acc0, 0, 0, 0);
                    acc1 = __builtin_amdgcn_mfma_f32_16x16x32_bf16(Bf[(T1*4 + s)*64 + L], fh[s], acc1, 0, 0, 0);
                }
                f32x2 e00 = tanh2(acc0.xy), e01 = tanh2(acc0.zw);
                f32x2 e10 = tanh2(acc1.xy), e11 = tanh2(acc1.zw);
                short8 ef = mk8(pkv(e00), pkv(e01), pkv(e10), pkv(e11));
                vacc = __builtin_amdgcn_mfma_f32_16x16x32_bf16(W3Af[qi*64 + L], ef, vacc, 0, 0, 0);
                __builtin_amdgcn_sched_barrier(0);
            }
            vAx = __shfl(vacc[0], m, 64);
            vAy = __shfl(vacc[1], m, 64);
            vAz = __shfl(vacc[2], m, 64);
        }

        float dt_ = copysignf(fminf(fabsf(off_), DT_MAXF), off_);
        float hd = 0.5f * dt_;
        float mx = px_ - hd*(vAx + b30);
        float my = py_ - hd*(vAy + b31);
        float mz = pz_ - hd*(vAz + b32);
        float tm = tc_ - hd;

        // ======== eval B: v + Jacobian at midpoint ========
        float vx, vy, vz;
        floatx4 V = Z4, J0 = Z4, J1 = Z4, J2 = Z4;
        {
            short8 xf = xyzt_frag(mx, my, mz, tm, q);
            floatx4 z[8];
            #pragma unroll
            for (int t = 0; t < 8; ++t)
                z[t] = __builtin_amdgcn_mfma_f32_16x16x32_bf16(W1Af[t*64 + L], xf, base1C[t], 0, 0, 0);
            short8 fh[4], fd0[4], fd1[4], fd2[4];
            #pragma unroll
            for (int s = 0; s < 4; ++s) {
                unsigned uh[4], u0[4], u1[4], u2[4];
                #pragma unroll
                for (int hf = 0; hf < 2; ++hf) {
                    int t = 2*s + hf;
                    f32x2 h0 = tanh2(z[t].xy), h1 = tanh2(z[t].zw);
                    f32x2 s0 = fma2(-h0, h0, sp2(1.0f));
                    f32x2 s1 = fma2(-h1, h1, sp2(1.0f));
                    floatx4 wx = WdX4[t*4 + q], wy = WdY4[t*4 + q], wz = WdZ4[t*4 + q];
                    uh[2*hf+0] = pkv(h0);         uh[2*hf+1] = pkv(h1);
                    u0[2*hf+0] = pkv(s0 * wx.xy); u0[2*hf+1] = pkv(s1 * wx.zw);
                    u1[2*hf+0] = pkv(s0 * wy.xy); u1[2*hf+1] = pkv(s1 * wy.zw);
                    u2[2*hf+0] = pkv(s0 * wz.xy); u2[2*hf+1] = pkv(s1 * wz.zw);
                }
                fh[s]  = mk8(uh[0], uh[1], uh[2], uh[3]);
                fd0[s] = mk8(u0[0], u0[1], u0[2], u0[3]);
                fd1[s] = mk8(u1[0], u1[1], u1[2], u1[3]);
                fd2[s] = mk8(u2[0], u2[1], u2[2], u2[3]);
            }
            __builtin_amdgcn_sched_barrier(0);
            // quarter qi = one L3 slice: tiles 2qi,2qi+1, all 4 chains, post,
            // 4 L3 MFMAs.
            #pragma unroll
            for (int qi = 0; qi < 4; ++qi) {
                const int T0 = 2*qi, T1 = 2*qi + 1;
                floatx4 aH0, aH1, aD00, aD01, aD10, aD11, aD20, aD21;
                {
                    short8 A0 = Bf[(T0*4 + 0)*64 + L];
                    short8 A1 = Bf[(T1*4 + 0)*64 + L];
                    aH0  = __builtin_amdgcn_mfma_f32_16x16x32_bf16(A0, fh[0],  b2C4[T0*4 + q], 0, 0, 0);
                    aH1  = __builtin_amdgcn_mfma_f32_16x16x32_bf16(A1, fh[0],  b2C4[T1*4 + q], 0, 0, 0);
                    aD00 = __builtin_amdgcn_mfma_f32_16x16x32_bf16(A0, fd0[0], Z4, 0, 0, 0);
                    aD01 = __builtin_amdgcn_mfma_f32_16x16x32_bf16(A1, fd0[0], Z4, 0, 0, 0);
                    aD10 = __builtin_amdgcn_mfma_f32_16x16x32_bf16(A0, fd1[0], Z4, 0, 0, 0);
                    aD11 = __builtin_amdgcn_mfma_f32_16x16x32_bf16(A1, fd1[0], Z4, 0, 0, 0);
                    aD20 = __builtin_amdgcn_mfma_f32_16x16x32_bf16(A0, fd2[0], Z4, 0, 0, 0);
                    aD21 = __builtin_amdgcn_mfma_f32_16x16x32_bf16(A1, fd2[0], Z4, 0, 0, 0);
                }
                #pragma unroll
                for (int s = 1; s < 4; ++s) {
                    short8 A0 = Bf[(T0*4 + s)*64 + L];
                    short8 A1 = Bf[(T1*4 + s)*64 + L];
                    aH0  = __builtin_amdgcn_mfma_f32_16x16x32_bf16(A0, fh[s],  aH0,  0, 0, 0);
                    aH1  = __builtin_amdgcn_mfma_f32_16x16x32_bf16(A1, fh[s],  aH1,  0, 0, 0);
                    aD00 = __builtin_amdgcn_mfma_f32_16x16x32_bf16(A0, fd0[s], aD00, 0, 0, 0);
                    aD01 = __builtin_amdgcn_mfma_f32_16x16x32_bf16(A1, fd0[s], aD01, 0, 0, 0);
                    aD10 = __builtin_amdgcn_mfma_f32_16x16x32_bf16(A0, fd1[s], aD10, 0, 0, 0);
                    aD11 = __builtin_amdgcn_mfma_f32_16x16x32_bf16(A1, fd1[s], aD11, 0, 0, 0);
                    aD20 = __builtin_amdgcn_mfma_f32_16x16x32_bf16(A0, fd2[s], aD20, 0, 0, 0);
                    aD21 = __builtin_amdgcn_mfma_f32_16x16x32_bf16(A1, fd2[s], aD21, 0, 0, 0);
                }
                // post for this slice: h2/s2/dd -> e-frags -> 4 L3 MFMAs
                f32x2 h0 = tanh2(aH0.xy), h1 = tanh2(aH0.zw);
                f32x2 h2v = tanh2(aH1.xy), h3 = tanh2(aH1.zw);
                f32x2 s0 = fma2(-h0, h0, sp2(1.0f));
                f32x2 s1 = fma2(-h1, h1, sp2(1.0f));
                f32x2 s2v = fma2(-h2v, h2v, sp2(1.0f));
                f32x2 s3 = fma2(-h3, h3, sp2(1.0f));
                short8 eh = mk8(pkv(h0), pkv(h1), pkv(h2v), pkv(h3));
                short8 e0 = mk8(pkv(s0*aD00.xy), pkv(s1*aD00.zw), pkv(s2v*aD01.xy), pkv(s3*aD01.zw));
                short8 e1 = mk8(pkv(s0*aD10.xy), pkv(s1*aD10.zw), pkv(s2v*aD11.xy), pkv(s3*aD11.zw));
                short8 e2 = mk8(pkv(s0*aD20.xy), pkv(s1*aD20.zw), pkv(s2v*aD21.xy), pkv(s3*aD21.zw));
                const short8 WA = W3Af[qi*64 + L];
                V  = __builtin_amdgcn_mfma_f32_16x16x32_bf16(WA, eh, V,  0, 0, 0);
                J0 = __builtin_amdgcn_mfma_f32_16x16x32_bf16(WA, e0, J0, 0, 0, 0);
                J1 = __builtin_amdgcn_mfma_f32_16x16x32_bf16(WA, e1, J1, 0, 0, 0);
                J2 = __builtin_amdgcn_mfma_f32_16x16x32_bf16(WA, e2, J2, 0, 0, 0);
                __builtin_amdgcn_sched_barrier(0);
            }
            vx = __shfl(V[0], m, 64) + b30;
            vy = __shfl(V[1], m, 64) + b31;
            vz = __shfl(V[2], m, 64) + b32;
            // Jr stays LOCAL: point m's Jacobian rows live in its q==0 lane's
            // J0..J2 regs 0..2 (other q-lanes hold zero rows -> harmless D).
        }

        // def + state update. J{k}[o] = dJ_o/dx_k (valid on q==0; 0 elsewhere).
        {
            f32x2 ndp[3]; float nds[3];
            #pragma unroll
            for (int o = 0; o < 3; ++o) {
                f32x2 tp = J0[o] * Dp[0];
                tp = fma2(sp2(J1[o]), Dp[1], tp);
                tp = fma2(sp2(J2[o]), Dp[2], tp);
                ndp[o] = fma2(sp2(-dt_), tp, Dp[o]);
                float ts = J0[o]*Ds[0];
                ts = fmaf(J1[o], Ds[1], ts);
                ts = fmaf(J2[o], Ds[2], ts);
                nds[o] = fmaf(-dt_, ts, Ds[o]);
            }
            #pragma unroll
            for (int o = 0; o < 3; ++o) { Dp[o] = ndp[o]; Ds[o] = nds[o]; }
        }
        px_ = fmaf(-dt_, vx, px_);
        py_ = fmaf(-dt_, vy, py_);
        pz_ = fmaf(-dt_, vz, pz_);
        tc_  -= dt_;
        off_ -= dt_;
    }

    // ---- output: q==0 lane of each point writes xyz + deform
    if (q == 0) {
        out[p*3+0] = px_; out[p*3+1] = py_; out[p*3+2] = pz_;
        float* o9 = out + (size_t)N*3 + (size_t)p*9;
        #pragma unroll
        for (int o = 0; o < 3; ++o) {
            o9[o*3+0] = Dp[o][0];
            o9[o*3+1] = Dp[o][1];
            o9[o*3+2] = Ds[o];
        }
    }
}

extern "C" void kernel_launch(void* const* d_in, const int* in_sizes, int n_in,
                              void* d_out, int out_size, void* d_ws, size_t ws_size,
                              hipStream_t stream) {
    const float* code = (const float*)d_in[0];
    const float* pos  = (const float*)d_in[1];
    const float* t1   = (const float*)d_in[2];
    const float* t2   = (const float*)d_in[3];
    const float* W1   = (const float*)d_in[4];
    const float* b1   = (const float*)d_in[5];
    const float* W2   = (const float*)d_in[6];
    const float* b2   = (const float*)d_in[7];
    const float* W3   = (const float*)d_in[8];
    const float* b3   = (const float*)d_in[9];
    float* out = (float*)d_out;
    const int N = in_sizes[1] / 3;           // 131072
    const int blocks = N / PPB;              // 2048
    const int pblocks = (N + 255) / 256;

    // Tiered workspace use (each tier == a previously-benched behavior):
    //   full: counters + wpack + perm;  mid: counters + perm;  none: identity.
    const size_t need_perm = 128 + (size_t)N * sizeof(int);
    const size_t need_full = 128 + (size_t)WPACK_U4 * 16 + (size_t)N * sizeof(int);
    int* perm = nullptr;
    uint4* wpack = nullptr;
    if (d_ws && ws_size >= need_full) {
        unsigned* cnt = (unsigned*)d_ws;
        wpack = (uint4*)((char*)d_ws + 128);
        perm  = (int*)((char*)d_ws + 128 + (size_t)WPACK_U4 * 16);
        hipMemsetAsync(d_ws, 0, 128, stream);
        prep_pack<<<20, 256, 0, stream>>>(W1, W2, W3, b2, wpack);
        prep_hist<<<pblocks, 256, 0, stream>>>(t1, t2, cnt, N);
        prep_prefix<<<1, 64, 0, stream>>>(cnt);
        prep_scatter<<<pblocks, 256, 0, stream>>>(t1, t2, cnt, perm, N);
    } else if (d_ws && ws_size >= need_perm) {
        unsigned* cnt = (unsigned*)d_ws;
        perm = (int*)((char*)d_ws + 128);
        hipMemsetAsync(d_ws, 0, 128, stream);
        prep_hist<<<pblocks, 256, 0, stream>>>(t1, t2, cnt, N);
        prep_prefix<<<1, 64, 0, stream>>>(cnt);
        prep_scatter<<<pblocks, 256, 0, stream>>>(t1, t2, cnt, perm, N);
    }
    velwarp<<<blocks, 256, 0, stream>>>(code, pos, t1, t2, W1, b1, W2, b2, W3, b3,
                                        out, perm, wpack, N);
}

// Round 13
// 263.382 us; speedup vs baseline: 4.7869x; 1.0358x over previous
//
#include <hip/hip_runtime.h>
#include <hip/hip_bf16.h>

#define H 128
#define NSTEPS 8
#define DT_MAXF 0.125f
#define WAVES 4
#define PPW 16            // points per wave (one 16x16 MFMA N-tile)
#define PPB (WAVES*PPW)   // 64 points per block
#define WPACK_U4 4992     // packed-weights size in uint4 (79872 B)
#define HBLK 512          // max pblocks supported by fused scatter
#define PACKB 20          // blocks appended to K1 for weight packing

typedef __attribute__((ext_vector_type(8))) short short8;   // 8 bf16 MFMA A/B frag
typedef __attribute__((ext_vector_type(4))) float floatx4;  // MFMA C/D frag
typedef __attribute__((ext_vector_type(2))) float f32x2;    // packed-FP32 pair (v_pk_*_f32)

__device__ __forceinline__ f32x2 sp2(float v) { return (f32x2){v, v}; }
__device__ __forceinline__ f32x2 fma2(f32x2 a, f32x2 b, f32x2 c) {
    return __builtin_elementwise_fma(a, b, c);              // -> v_pk_fma_f32
}
// tanh pair, merged-rcp form (R17): 1/(ea+1) = (eb+1)*rcp((ea+1)(eb+1)).
__device__ __forceinline__ f32x2 tanh2(f32x2 x) {
    f32x2 y = x * 2.8853900817779268f;
    f32x2 e; e[0] = __builtin_amdgcn_exp2f(y[0]); e[1] = __builtin_amdgcn_exp2f(y[1]);
    f32x2 ep = e + 1.0f;
    float rt = __builtin_amdgcn_rcpf(ep[0] * ep[1]);
    f32x2 eps = __builtin_shufflevector(ep, ep, 1, 0);
    f32x2 r = eps * sp2(rt);
    return fma2(sp2(-2.0f), r, sp2(1.0f));
}
__device__ __forceinline__ unsigned f2bf(float x) {           // fp32 -> bf16 bits, RNE
    unsigned u = __float_as_uint(x);
    return (u + 0x7FFFu + ((u >> 16) & 1u)) >> 16;
}
__device__ __forceinline__ unsigned pk2(float a, float b) {   // packed bf16 cvt
    union { __hip_bfloat162 h; unsigned u; } U;
    U.h = __float22bfloat162_rn(make_float2(a, b));
    return U.u;
}
__device__ __forceinline__ unsigned pkv(f32x2 v) { return pk2(v[0], v[1]); }
__device__ __forceinline__ short8 mk8(unsigned a, unsigned b, unsigned c, unsigned d) {
    union { unsigned u[4]; short8 s; } U;
    U.u[0] = a; U.u[1] = b; U.u[2] = c; U.u[3] = d; return U.s;
}
// xyzt B-frag, hi/lo split bf16. Lane q=0 carries hi+lo, q=1 carries hi, q>=2 zero.
__device__ __forceinline__ short8 xyzt_frag(float x, float y, float z, float t, int q) {
    unsigned hx = f2bf(x), hy = f2bf(y), hz = f2bf(z), ht = f2bf(t);
    float lx = x - __uint_as_float(hx << 16);
    float ly = y - __uint_as_float(hy << 16);
    float lz = z - __uint_as_float(hz << 16);
    float lt = t - __uint_as_float(ht << 16);
    unsigned w0 = hx | (hy << 16), w1 = hz | (ht << 16);
    unsigned w2 = pk2(lx, ly),     w3 = pk2(lz, lt);
    union { unsigned u[4]; short8 s; } F;
    F.u[0] = (q < 2)  ? w0 : 0u;
    F.u[1] = (q < 2)  ? w1 : 0u;
    F.u[2] = (q == 0) ? w2 : 0u;
    F.u[3] = (q == 0) ? w3 : 0u;
    return F.s;
}

__device__ __forceinline__ int step_bucket(float t1v, float t2v) {
    float off = fabsf(t1v - t2v);
    int b = (int)ceilf(off * 8.0f);
    return min(max(b, 0), 8);
}

// ---- R21 weight pack (device fn; called from K1's tail blocks) ----
// Layout (uint4): [0,2048) W1b frags; [2048,4096) W2 frags; [4096,4608) W1A;
// [4608,4864) W3A; [4864,4992) WdX|WdY|WdZ|b2C.
__device__ void pack_body(int gid, int stride,
                          const float* __restrict__ W1, const float* __restrict__ W2,
                          const float* __restrict__ W3, const float* __restrict__ b2,
                          uint4* __restrict__ wp) {
    for (int e = gid; e < 1024; e += stride) {
        int t = e >> 7, rem = e & 127;
        int c = rem >> 6, l = rem & 63;
        int qq = l >> 4, mm = l & 15;
        int u = t*16 + mm;
        int g0 = c*32 + qq*4, g1 = g0 + 16;
        unsigned hh[8]; float lo[8];
        #pragma unroll
        for (int j = 0; j < 4; ++j) {
            float w0 = W1[(g0+j)*H + u];
            float w1 = W1[(g1+j)*H + u];
            hh[j]   = f2bf(w0); lo[j]   = w0 - __uint_as_float(hh[j]   << 16);
            hh[4+j] = f2bf(w1); lo[4+j] = w1 - __uint_as_float(hh[4+j] << 16);
        }
        wp[((t*2+c)*2+0)*64 + l] = make_uint4(hh[0]|(hh[1]<<16), hh[2]|(hh[3]<<16),
                                              hh[4]|(hh[5]<<16), hh[6]|(hh[7]<<16));
        wp[((t*2+c)*2+1)*64 + l] = make_uint4(pk2(lo[0],lo[1]), pk2(lo[2],lo[3]),
                                              pk2(lo[4],lo[5]), pk2(lo[6],lo[7]));
    }
    for (int ch = gid; ch < 2048; ch += stride) {
        int ln = ch & 63, ts = ch >> 6;
        int s = ts & 3, t = ts >> 2;
        int qq = ln >> 4, n = t*16 + (ln & 15);
        int u0 = s*32 + qq*4, u1 = u0 + 16;
        unsigned w0 = f2bf(W2[(u0+0)*H+n]) | (f2bf(W2[(u0+1)*H+n]) << 16);
        unsigned w1 = f2bf(W2[(u0+2)*H+n]) | (f2bf(W2[(u0+3)*H+n]) << 16);
        unsigned w2 = f2bf(W2[(u1+0)*H+n]) | (f2bf(W2[(u1+1)*H+n]) << 16);
        unsigned w3v = f2bf(W2[(u1+2)*H+n]) | (f2bf(W2[(u1+3)*H+n]) << 16);
        wp[2048 + ch] = make_uint4(w0, w1, w2, w3v);
    }
    for (int e = gid; e < 512; e += stride) {
        int t = e >> 6, l = e & 63;
        int u = t*16 + (l & 15), qq = l >> 4;
        unsigned hb[4], lb[4];
        #pragma unroll
        for (int c = 0; c < 4; ++c) {
            float wv = W1[(64 + c)*H + u];
            unsigned hh = f2bf(wv);
            float wl = wv - __uint_as_float(hh << 16);
            hb[c] = hh; lb[c] = f2bf(wl);
        }
        unsigned hi01 = hb[0] | (hb[1] << 16), hi23 = hb[2] | (hb[3] << 16);
        unsigned lo01 = lb[0] | (lb[1] << 16), lo23 = lb[2] | (lb[3] << 16);
        uint4 o;
        if (qq == 0)      o = make_uint4(hi01, hi23, hi01, hi23);
        else if (qq == 1) o = make_uint4(lo01, lo23, 0u, 0u);
        else              o = make_uint4(0u, 0u, 0u, 0u);
        wp[4096 + e] = o;
    }
    for (int e = gid; e < 256; e += stride) {
        int s = e >> 6, l = e & 63;
        int a = l & 15, qq = l >> 4;
        uint4 o = make_uint4(0u, 0u, 0u, 0u);
        if (a < 3) {
            int u0 = s*32 + qq*4, u1 = u0 + 16;
            o.x = f2bf(W3[(u0+0)*3+a]) | (f2bf(W3[(u0+1)*3+a]) << 16);
            o.y = f2bf(W3[(u0+2)*3+a]) | (f2bf(W3[(u0+3)*3+a]) << 16);
            o.z = f2bf(W3[(u1+0)*3+a]) | (f2bf(W3[(u1+1)*3+a]) << 16);
            o.w = f2bf(W3[(u1+2)*3+a]) | (f2bf(W3[(u1+3)*3+a]) << 16);
        }
        wp[4608 + e] = o;
    }
    for (int i = gid; i < 128; i += stride) {
        int sec = i >> 5, k = i & 31;
        float4 v = (sec < 3) ? ((const float4*)(W1 + (size_t)(64+sec)*H))[k]
                             : ((const float4*)b2)[k];
        wp[4864 + i] = *(const uint4*)&v;
    }
}

// ---- R22 fused pre-pass: 2 kernels instead of 5 dispatches ----
// K1: per-block 9-bin histogram (no global atomics, no memset) + weight pack
//     in the tail PACKB blocks.
__global__ void prep_hist2(const float* __restrict__ t1g, const float* __restrict__ t2g,
                           unsigned* __restrict__ cnt2, int N, int pblocks,
                           const float* __restrict__ W1, const float* __restrict__ W2,
                           const float* __restrict__ W3, const float* __restrict__ b2,
                           uint4* __restrict__ wp) {
    if ((int)blockIdx.x >= pblocks) {
        pack_body((blockIdx.x - pblocks)*256 + threadIdx.x, PACKB*256, W1, W2, W3, b2, wp);
        return;
    }
    __shared__ unsigned h[9];
    if (threadIdx.x < 9) h[threadIdx.x] = 0u;
    __syncthreads();
    int i = blockIdx.x * 256 + threadIdx.x;
    if (i < N) atomicAdd(&h[step_bucket(t1g[i], t2g[i])], 1u);
    __syncthreads();
    if (threadIdx.x < 9) cnt2[blockIdx.x*9 + threadIdx.x] = h[threadIdx.x];
}
// K2: each block derives the exact global slot base for its items from the
// full per-block histogram table (deterministic -> valid permutation), then
// scatters. Descending bucket order = LPT (R20).
__global__ void prep_scatter2(const float* __restrict__ t1g, const float* __restrict__ t2g,
                              const unsigned* __restrict__ cnt2, int* __restrict__ perm,
                              int N, int pblocks) {
    __shared__ unsigned cs[HBLK*9];
    __shared__ unsigned T9[9], O9[9], base9[9], alloc9[9];
    const int b = blockIdx.x, tid = threadIdx.x;
    for (int i = tid; i < pblocks*9; i += 256) cs[i] = cnt2[i];
    if (tid < 9) alloc9[tid] = 0u;
    __syncthreads();
    if (tid < 9) {
        unsigned O = 0, T = 0;
        for (int i = 0; i < pblocks; ++i) {
            unsigned c = cs[i*9 + tid];
            if (i < b) O += c;
            T += c;
        }
        T9[tid] = T; O9[tid] = O;
    }
    __syncthreads();
    if (tid < 9) {
        unsigned G = 0;
        for (int k = 8; k > tid; --k) G += T9[k];
        base9[tid] = G + O9[tid];
    }
    __syncthreads();
    int i = b*256 + tid;
    if (i < N) {
        int k = step_bucket(t1g[i], t2g[i]);
        unsigned r = atomicAdd(&alloc9[k], 1u);
        perm[base9[k] + r] = i;
    }
}

// ---- mid-tier fallback pre-pass (R19/R20 scheme, needs memset) ----
__global__ void prep_hist(const float* __restrict__ t1g, const float* __restrict__ t2g,
                          unsigned* cnt, int N) {
    __shared__ unsigned h[9];
    if (threadIdx.x < 9) h[threadIdx.x] = 0u;
    __syncthreads();
    int i = blockIdx.x * 256 + threadIdx.x;
    if (i < N) atomicAdd(&h[step_bucket(t1g[i], t2g[i])], 1u);
    __syncthreads();
    if (threadIdx.x < 9 && h[threadIdx.x]) atomicAdd(&cnt[threadIdx.x], h[threadIdx.x]);
}
__global__ void prep_prefix(unsigned* cnt) {
    if (threadIdx.x == 0) {
        unsigned run = 0;
        for (int b = 8; b >= 0; --b) { unsigned c = cnt[b]; cnt[9 + b] = run; run += c; }
    }
}
__global__ void prep_scatter(const float* __restrict__ t1g, const float* __restrict__ t2g,
                             unsigned* cnt, int* __restrict__ perm, int N) {
    __shared__ unsigned h[9];
    __shared__ unsigned base[9];
    if (threadIdx.x < 9) h[threadIdx.x] = 0u;
    __syncthreads();
    int i = blockIdx.x * 256 + threadIdx.x;
    int b = 0; unsigned r = 0;
    if (i < N) {
        b = step_bucket(t1g[i], t2g[i]);
        r = atomicAdd(&h[b], 1u);
    }
    __syncthreads();
    if (threadIdx.x < 9 && h[threadIdx.x])
        base[threadIdx.x] = atomicAdd(&cnt[9 + threadIdx.x], h[threadIdx.x]);
    __syncthreads();
    if (i < N) perm[base[b] + r] = i;
}

// R12: L1/L2/L3 on the MFMA pipe (pi-permuted k; zero cross-lane repack).
// R18/R19: sorted early-exit (374 -> 241us). R20: base1C via MFMA (-> 210).
// R21: weights packed once (-> 199). R22: base1C A-frags read DIRECTLY from
// wpack global (L2-broadcast across blocks) -- drops the W1b LDS staging
// phase + one __syncthreads; W2 frags copied to LDS once at entry.
__global__ __launch_bounds__(256, 2)
void velwarp(const float* __restrict__ code, const float* __restrict__ pos,
             const float* __restrict__ t1g, const float* __restrict__ t2g,
             const float* __restrict__ W1, const float* __restrict__ b1,
             const float* __restrict__ W2, const float* __restrict__ b2,
             const float* __restrict__ W3, const float* __restrict__ b3,
             float* __restrict__ out, const int* __restrict__ perm,
             const uint4* __restrict__ wpack, int N)
{
    __shared__ __align__(16) uint4 WbufU[2048];   // 32KB: W2 bf16 frags (fast path); W1b then W2 (fallback)
    __shared__ __align__(16) uint4 W1AU[8*64];    // 8KB : layer-1 A-frags (xyzt rows, hi/lo split)
    __shared__ __align__(16) uint4 W3AU[4*64];    // 4KB : layer-3 A-frags (W3^T, pi-permuted)
    __shared__ __align__(16) floatx4 WdX4[32];    // W1[64][u] in C/D order (= row-linear)
    __shared__ __align__(16) floatx4 WdY4[32];    // W1[65][u]
    __shared__ __align__(16) floatx4 WdZ4[32];    // W1[66][u]
    __shared__ __align__(16) floatx4 b2C4[32];    // b2 in C/D order

    const int tid = threadIdx.x;
    const int L   = tid & 63;
    const int m   = L & 15;      // this lane's point (C/D col)
    const int q   = L >> 4;      // C/D row group = q*4+reg; B-frag k-quad
    const int pb  = blockIdx.x * PPB + (tid >> 6) * PPW;
    const int p   = perm ? perm[pb + m] : (pb + m);   // global point index

    floatx4 base1C[8];

    if (wpack) {
        // ---- R22 fast path: W2 frags + tables -> LDS; base1C frags stay global
        #pragma unroll 4
        for (int i = tid; i < 2048; i += 256) WbufU[i] = wpack[2048 + i];
        #pragma unroll 2
        for (int i = tid; i < 512; i += 256) W1AU[i] = wpack[4096 + i];
        W3AU[tid & 255] = wpack[4608 + (tid & 255)];
        if (tid < 128) {
            int sec = tid >> 5, k = tid & 31;
            uint4 v = wpack[4864 + tid];
            floatx4 f = *(const floatx4*)&v;
            if (sec == 0)      WdX4[k] = f;
            else if (sec == 1) WdY4[k] = f;
            else if (sec == 2) WdZ4[k] = f;
            else               b2C4[k] = f;
        }
        // base1C via MFMA, A-frags from global wpack (coalesced, L2-shared)
        {
            const float4* crow4 = (const float4*)(code + (size_t)p * 64);
            short8 Bh[2], Bl[2];
            #pragma unroll
            for (int c = 0; c < 2; ++c) {
                float4 a = crow4[c*8 + q];
                float4 b = crow4[c*8 + 4 + q];
                unsigned h0 = f2bf(a.x), h1 = f2bf(a.y), h2 = f2bf(a.z), h3 = f2bf(a.w);
                unsigned g0 = f2bf(b.x), g1 = f2bf(b.y), g2 = f2bf(b.z), g3 = f2bf(b.w);
                float l0 = a.x - __uint_as_float(h0<<16), l1 = a.y - __uint_as_float(h1<<16);
                float l2 = a.z - __uint_as_float(h2<<16), l3 = a.w - __uint_as_float(h3<<16);
                float m0 = b.x - __uint_as_float(g0<<16), m1 = b.y - __uint_as_float(g1<<16);
                float m2 = b.z - __uint_as_float(g2<<16), m3 = b.w - __uint_as_float(g3<<16);
                Bh[c] = mk8(h0|(h1<<16), h2|(h3<<16), g0|(g1<<16), g2|(g3<<16));
                Bl[c] = mk8(pk2(l0,l1), pk2(l2,l3), pk2(m0,m1), pk2(m2,m3));
            }
            const short8* Wb = (const short8*)wpack;   // [t][c][term][64], global
            #pragma unroll
            for (int t = 0; t < 8; ++t) {
                floatx4 z = *(const floatx4*)&b1[t*16 + q*4];
                short8 Wh0 = Wb[((t*2+0)*2+0)*64 + L];
                short8 Wh1 = Wb[((t*2+1)*2+0)*64 + L];
                short8 Wl0 = Wb[((t*2+0)*2+1)*64 + L];
                short8 Wl1 = Wb[((t*2+1)*2+1)*64 + L];
                z = __builtin_amdgcn_mfma_f32_16x16x32_bf16(Wh0, Bh[0], z, 0, 0, 0);
                z = __builtin_amdgcn_mfma_f32_16x16x32_bf16(Wh1, Bh[1], z, 0, 0, 0);
                z = __builtin_amdgcn_mfma_f32_16x16x32_bf16(Wh0, Bl[0], z, 0, 0, 0);
                z = __builtin_amdgcn_mfma_f32_16x16x32_bf16(Wh1, Bl[1], z, 0, 0, 0);
                z = __builtin_amdgcn_mfma_f32_16x16x32_bf16(Wl0, Bh[0], z, 0, 0, 0);
                z = __builtin_amdgcn_mfma_f32_16x16x32_bf16(Wl1, Bh[1], z, 0, 0, 0);
                base1C[t] = z;
            }
        }
        __syncthreads();
    } else {
        // ---- fallback: in-kernel pack (R21 structure, identical math)
        for (int e = tid; e < 1024; e += 256) {
            int t = e >> 7, rem = e & 127;
            int c = rem >> 6, l = rem & 63;
            int qq = l >> 4, mm = l & 15;
            int u = t*16 + mm;
            int g0 = c*32 + qq*4, g1 = g0 + 16;
            unsigned hh[8]; float lo[8];
            #pragma unroll
            for (int j = 0; j < 4; ++j) {
                float w0 = W1[(g0+j)*H + u];
                float w1 = W1[(g1+j)*H + u];
                hh[j]   = f2bf(w0); lo[j]   = w0 - __uint_as_float(hh[j]   << 16);
                hh[4+j] = f2bf(w1); lo[4+j] = w1 - __uint_as_float(hh[4+j] << 16);
            }
            WbufU[((t*2+c)*2+0)*64 + l] = make_uint4(hh[0]|(hh[1]<<16), hh[2]|(hh[3]<<16),
                                                     hh[4]|(hh[5]<<16), hh[6]|(hh[7]<<16));
            WbufU[((t*2+c)*2+1)*64 + l] = make_uint4(pk2(lo[0],lo[1]), pk2(lo[2],lo[3]),
                                                     pk2(lo[4],lo[5]), pk2(lo[6],lo[7]));
        }
        for (int e = tid; e < 512; e += 256) {
            int t = e >> 6, l = e & 63;
            int u = t*16 + (l & 15), qq = l >> 4;
            unsigned hb[4], lb[4];
            #pragma unroll
            for (int c = 0; c < 4; ++c) {
                float wv = W1[(64 + c)*H + u];
                unsigned hh = f2bf(wv);
                float wl = wv - __uint_as_float(hh << 16);
                hb[c] = hh; lb[c] = f2bf(wl);
            }
            unsigned hi01 = hb[0] | (hb[1] << 16), hi23 = hb[2] | (hb[3] << 16);
            unsigned lo01 = lb[0] | (lb[1] << 16), lo23 = lb[2] | (lb[3] << 16);
            uint4 o;
            if (qq == 0)      o = make_uint4(hi01, hi23, hi01, hi23);
            else if (qq == 1) o = make_uint4(lo01, lo23, 0u, 0u);
            else              o = make_uint4(0u, 0u, 0u, 0u);
            W1AU[e] = o;
        }
        for (int e = tid; e < 256; e += 256) {
            int s = e >> 6, l = e & 63;
            int a = l & 15, qq = l >> 4;
            uint4 o = make_uint4(0u, 0u, 0u, 0u);
            if (a < 3) {
                int u0 = s*32 + qq*4, u1 = u0 + 16;
                o.x = f2bf(W3[(u0+0)*3+a]) | (f2bf(W3[(u0+1)*3+a]) << 16);
                o.y = f2bf(W3[(u0+2)*3+a]) | (f2bf(W3[(u0+3)*3+a]) << 16);
                o.z = f2bf(W3[(u1+0)*3+a]) | (f2bf(W3[(u1+1)*3+a]) << 16);
                o.w = f2bf(W3[(u1+2)*3+a]) | (f2bf(W3[(u1+3)*3+a]) << 16);
            }
            W3AU[e] = o;
        }
        if (tid < 32) {
            WdX4[tid] = ((const floatx4*)(W1 + (size_t)64*H))[tid];
            WdY4[tid] = ((const floatx4*)(W1 + (size_t)65*H))[tid];
            WdZ4[tid] = ((const floatx4*)(W1 + (size_t)66*H))[tid];
            b2C4[tid] = ((const floatx4*)b2)[tid];
        }
        __syncthreads();
        {
            const float4* crow4 = (const float4*)(code + (size_t)p * 64);
            short8 Bh[2], Bl[2];
            #pragma unroll
            for (int c = 0; c < 2; ++c) {
                float4 a = crow4[c*8 + q];
                float4 b = crow4[c*8 + 4 + q];
                unsigned h0 = f2bf(a.x), h1 = f2bf(a.y), h2 = f2bf(a.z), h3 = f2bf(a.w);
                unsigned g0 = f2bf(b.x), g1 = f2bf(b.y), g2 = f2bf(b.z), g3 = f2bf(b.w);
                float l0 = a.x - __uint_as_float(h0<<16), l1 = a.y - __uint_as_float(h1<<16);
                float l2 = a.z - __uint_as_float(h2<<16), l3 = a.w - __uint_as_float(h3<<16);
                float m0 = b.x - __uint_as_float(g0<<16), m1 = b.y - __uint_as_float(g1<<16);
                float m2 = b.z - __uint_as_float(g2<<16), m3 = b.w - __uint_as_float(g3<<16);
                Bh[c] = mk8(h0|(h1<<16), h2|(h3<<16), g0|(g1<<16), g2|(g3<<16));
                Bl[c] = mk8(pk2(l0,l1), pk2(l2,l3), pk2(m0,m1), pk2(m2,m3));
            }
            const short8* Wb = (const short8*)WbufU;
            #pragma unroll
            for (int t = 0; t < 8; ++t) {
                floatx4 z = *(const floatx4*)&b1[t*16 + q*4];
                short8 Wh0 = Wb[((t*2+0)*2+0)*64 + L];
                short8 Wh1 = Wb[((t*2+1)*2+0)*64 + L];
                short8 Wl0 = Wb[((t*2+0)*2+1)*64 + L];
                short8 Wl1 = Wb[((t*2+1)*2+1)*64 + L];
                z = __builtin_amdgcn_mfma_f32_16x16x32_bf16(Wh0, Bh[0], z, 0, 0, 0);
                z = __builtin_amdgcn_mfma_f32_16x16x32_bf16(Wh1, Bh[1], z, 0, 0, 0);
                z = __builtin_amdgcn_mfma_f32_16x16x32_bf16(Wh0, Bl[0], z, 0, 0, 0);
                z = __builtin_amdgcn_mfma_f32_16x16x32_bf16(Wh1, Bl[1], z, 0, 0, 0);
                z = __builtin_amdgcn_mfma_f32_16x16x32_bf16(Wl0, Bh[0], z, 0, 0, 0);
                z = __builtin_amdgcn_mfma_f32_16x16x32_bf16(Wl1, Bh[1], z, 0, 0, 0);
                base1C[t] = z;
            }
        }
        __syncthreads();   // W1b frag reads done before W2 overwrite
        for (int ch = tid; ch < 2048; ch += 256) {
            int ln = ch & 63, ts = ch >> 6;
            int s = ts & 3, t = ts >> 2;
            int qq = ln >> 4, n = t*16 + (ln & 15);
            int u0 = s*32 + qq*4, u1 = u0 + 16;
            unsigned w0 = f2bf(W2[(u0+0)*H+n]) | (f2bf(W2[(u0+1)*H+n]) << 16);
            unsigned w1 = f2bf(W2[(u0+2)*H+n]) | (f2bf(W2[(u0+3)*H+n]) << 16);
            unsigned w2 = f2bf(W2[(u1+0)*H+n]) | (f2bf(W2[(u1+1)*H+n]) << 16);
            unsigned w3v = f2bf(W2[(u1+2)*H+n]) | (f2bf(W2[(u1+3)*H+n]) << 16);
            WbufU[ch] = make_uint4(w0, w1, w2, w3v);
        }
        __syncthreads();
    }

    // ---- per-lane point state
    float px_ = pos[p*3+0], py_ = pos[p*3+1], pz_ = pos[p*3+2];
    float tc_ = t1g[p];
    float off_ = tc_ - t2g[p];
    f32x2 Dp[3]; float Ds[3];
    Dp[0] = (f32x2){1.f, 0.f}; Ds[0] = 0.f;
    Dp[1] = (f32x2){0.f, 1.f}; Ds[1] = 0.f;
    Dp[2] = (f32x2){0.f, 0.f}; Ds[2] = 1.f;
    const float b30 = b3[0], b31 = b3[1], b32 = b3[2];

    const short8* Bf   = (const short8*)WbufU;
    const short8* W1Af = (const short8*)W1AU;
    const short8* W3Af = (const short8*)W3AU;
    const floatx4 Z4 = {0.f, 0.f, 0.f, 0.f};

    for (int step = 0; step < NSTEPS; ++step) {
        // R18: remaining steps for this wave's 16 points are exact no-ops.
        if (!__any(off_ != 0.0f)) break;

        // ======== eval A: v(x,t) ========
        float vAx, vAy, vAz;
        {
            short8 xf = xyzt_frag(px_, py_, pz_, tc_, q);
            floatx4 z[8];
            #pragma unroll
            for (int t = 0; t < 8; ++t)
                z[t] = __builtin_amdgcn_mfma_f32_16x16x32_bf16(W1Af[t*64 + L], xf, base1C[t], 0, 0, 0);
            short8 fh[4];
            #pragma unroll
            for (int s = 0; s < 4; ++s) {
                f32x2 a0 = tanh2(z[2*s].xy),   a1 = tanh2(z[2*s].zw);
                f32x2 c0 = tanh2(z[2*s+1].xy), c1 = tanh2(z[2*s+1].zw);
                fh[s] = mk8(pkv(a0), pkv(a1), pkv(c0), pkv(c1));
            }
            __builtin_amdgcn_sched_barrier(0);
            floatx4 vacc = Z4;
            #pragma unroll
            for (int qi = 0; qi < 4; ++qi) {
                const int T0 = 2*qi, T1 = 2*qi + 1;
                floatx4 acc0 = __builtin_amdgcn_mfma_f32_16x16x32_bf16(
                    Bf[(T0*4 + 0)*64 + L], fh[0], b2C4[T0*4 + q], 0, 0, 0);
                floatx4 acc1 = __builtin_amdgcn_mfma_f32_16x16x32_bf16(
                    Bf[(T1*4 + 0)*64 + L], fh[0], b2C4[T1*4 + q], 0, 0, 0);
                #pragma unroll
                for (int s = 1; s < 4; ++s) {
                    acc0 = __builtin_amdgcn_mfma_f32_16x16x32_bf16(Bf[(T0*4 + s)*64 + L], fh[s], acc0, 0, 0, 0);
                    acc1 = __builtin_amdgcn_mfma_f32_16x16x32_bf16(Bf[(T1*4 + s)*64 + L], fh[s], acc1, 0, 0, 0);
                }
                f32x2 e00 = tanh2(acc0.xy), e01 = tanh2(acc0.zw);
                f32x2 e10 = tanh2(acc1.xy), e11 = tanh2(acc1.zw);
                short8 ef = mk8(pkv(e00), pkv(e01), pkv(e10), pkv(e11));
                vacc = __builtin_amdgcn_mfma_f32_16x16x32_bf16(W3Af[qi*64 + L], ef, vacc, 0, 0, 0);
                __builtin_amdgcn_sched_barrier(0);
            }
            vAx = __shfl(vacc[0], m, 64);
            vAy = __shfl(vacc[1], m, 64);
            vAz = __shfl(vacc[2], m, 64);
        }

        float dt_ = copysignf(fminf(fabsf(off_), DT_MAXF), off_);
        float hd = 0.5f * dt_;
        float mx = px_ - hd*(vAx + b30);
        float my = py_ - hd*(vAy + b31);
        float mz = pz_ - hd*(vAz + b32);
        float tm = tc_ - hd;

        // ======== eval B: v + Jacobian at midpoint ========
        float vx, vy, vz;
        floatx4 V = Z4, J0 = Z4, J1 = Z4, J2 = Z4;
        {
            short8 xf = xyzt_frag(mx, my, mz, tm, q);
            floatx4 z[8];
            #pragma unroll
            for (int t = 0; t < 8; ++t)
                z[t] = __builtin_amdgcn_mfma_f32_16x16x32_bf16(W1Af[t*64 + L], xf, base1C[t], 0, 0, 0);
            short8 fh[4], fd0[4], fd1[4], fd2[4];
            #pragma unroll
            for (int s = 0; s < 4; ++s) {
                unsigned uh[4], u0[4], u1[4], u2[4];
                #pragma unroll
                for (int hf = 0; hf < 2; ++hf) {
                    int t = 2*s + hf;
                    f32x2 h0 = tanh2(z[t].xy), h1 = tanh2(z[t].zw);
                    f32x2 s0 = fma2(-h0, h0, sp2(1.0f));
                    f32x2 s1 = fma2(-h1, h1, sp2(1.0f));
                    floatx4 wx = WdX4[t*4 + q], wy = WdY4[t*4 + q], wz = WdZ4[t*4 + q];
                    uh[2*hf+0] = pkv(h0);         uh[2*hf+1] = pkv(h1);
                    u0[2*hf+0] = pkv(s0 * wx.xy); u0[2*hf+1] = pkv(s1 * wx.zw);
                    u1[2*hf+0] = pkv(s0 * wy.xy); u1[2*hf+1] = pkv(s1 * wy.zw);
                    u2[2*hf+0] = pkv(s0 * wz.xy); u2[2*hf+1] = pkv(s1 * wz.zw);
                }
                fh[s]  = mk8(uh[0], uh[1], uh[2], uh[3]);
                fd0[s] = mk8(u0[0], u0[1], u0[2], u0[3]);
                fd1[s] = mk8(u1[0], u1[1], u1[2], u1[3]);
                fd2[s] = mk8(u2[0], u2[1], u2[2], u2[3]);
            }
            __builtin_amdgcn_sched_barrier(0);
            #pragma unroll
            for (int qi = 0; qi < 4; ++qi) {
                const int T0 = 2*qi, T1 = 2*qi + 1;
                floatx4 aH0, aH1, aD00, aD01, aD10, aD11, aD20, aD21;
                {
                    short8 A0 = Bf[(T0*4 + 0)*64 + L];
                    short8 A1 = Bf[(T1*4 + 0)*64 + L];
                    aH0  = __builtin_amdgcn_mfma_f32_16x16x32_bf16(A0, fh[0],  b2C4[T0*4 + q], 0, 0, 0);
                    aH1  = __builtin_amdgcn_mfma_f32_16x16x32_bf16(A1, fh[0],  b2C4[T1*4 + q], 0, 0, 0);
                    aD00 = __builtin_amdgcn_mfma_f32_16x16x32_bf16(A0, fd0[0], Z4, 0, 0, 0);
                    aD01 = __builtin_amdgcn_mfma_f32_16x16x32_bf16(A1, fd0[0], Z4, 0, 0, 0);
                    aD10 = __builtin_amdgcn_mfma_f32_16x16x32_bf16(A0, fd1[0], Z4, 0, 0, 0);
                    aD11 = __builtin_amdgcn_mfma_f32_16x16x32_bf16(A1, fd1[0], Z4, 0, 0, 0);
                    aD20 = __builtin_amdgcn_mfma_f32_16x16x32_bf16(A0, fd2[0], Z4, 0, 0, 0);
                    aD21 = __builtin_amdgcn_mfma_f32_16x16x32_bf16(A1, fd2[0], Z4, 0, 0, 0);
                }
                #pragma unroll
                for (int s = 1; s < 4; ++s) {
                    short8 A0 = Bf[(T0*4 + s)*64 + L];
                    short8 A1 = Bf[(T1*4 + s)*64 + L];
                    aH0  = __builtin_amdgcn_mfma_f32_16x16x32_bf16(A0, fh[s],  aH0,  0, 0, 0);
                    aH1  = __builtin_amdgcn_mfma_f32_16x16x32_bf16(A1, fh[s],  aH1,  0, 0, 0);
                    aD00 = __builtin_amdgcn_mfma_f32_16x16x32_bf16(A0, fd0[s], aD00, 0, 0, 0);
                    aD01 = __builtin_amdgcn_mfma_f32_16x16x32_bf16(A1, fd0[s], aD01, 0, 0, 0);
                    aD10 = __builtin_amdgcn_mfma_f32_16x16x32_bf16(A0, fd1[s], aD10, 0, 0, 0);
                    aD11 = __builtin_amdgcn_mfma_f32_16x16x32_bf16(A1, fd1[s], aD11, 0, 0, 0);
                    aD20 = __builtin_amdgcn_mfma_f32_16x16x32_bf16(A0, fd2[s], aD20, 0, 0, 0);
                    aD21 = __builtin_amdgcn_mfma_f32_16x16x32_bf16(A1, fd2[s], aD21, 0, 0, 0);
                }
                f32x2 h0 = tanh2(aH0.xy), h1 = tanh2(aH0.zw);
                f32x2 h2v = tanh2(aH1.xy), h3 = tanh2(aH1.zw);
                f32x2 s0 = fma2(-h0, h0, sp2(1.0f));
                f32x2 s1 = fma2(-h1, h1, sp2(1.0f));
                f32x2 s2v = fma2(-h2v, h2v, sp2(1.0f));
                f32x2 s3 = fma2(-h3, h3, sp2(1.0f));
                short8 eh = mk8(pkv(h0), pkv(h1), pkv(h2v), pkv(h3));
                short8 e0 = mk8(pkv(s0*aD00.xy), pkv(s1*aD00.zw), pkv(s2v*aD01.xy), pkv(s3*aD01.zw));
                short8 e1 = mk8(pkv(s0*aD10.xy), pkv(s1*aD10.zw), pkv(s2v*aD11.xy), pkv(s3*aD11.zw));
                short8 e2 = mk8(pkv(s0*aD20.xy), pkv(s1*aD20.zw), pkv(s2v*aD21.xy), pkv(s3*aD21.zw));
                const short8 WA = W3Af[qi*64 + L];
                V  = __builtin_amdgcn_mfma_f32_16x16x32_bf16(WA, eh, V,  0, 0, 0);
                J0 = __builtin_amdgcn_mfma_f32_16x16x32_bf16(WA, e0, J0, 0, 0, 0);
                J1 = __builtin_amdgcn_mfma_f32_16x16x32_bf16(WA, e1, J1, 0, 0, 0);
                J2 = __builtin_amdgcn_mfma_f32_16x16x32_bf16(WA, e2, J2, 0, 0, 0);
                __builtin_amdgcn_sched_barrier(0);
            }
            vx = __shfl(V[0], m, 64) + b30;
            vy = __shfl(V[1], m, 64) + b31;
            vz = __shfl(V[2], m, 64) + b32;
        }

        // def + state update. J{k}[o] valid on q==0 lanes; zero elsewhere.
        {
            f32x2 ndp[3]; float nds[3];
            #pragma unroll
            for (int o = 0; o < 3; ++o) {
                f32x2 tp = J0[o] * Dp[0];
                tp = fma2(sp2(J1[o]), Dp[1], tp);
                tp = fma2(sp2(J2[o]), Dp[2], tp);
                ndp[o] = fma2(sp2(-dt_), tp, Dp[o]);
                float ts = J0[o]*Ds[0];
                ts = fmaf(J1[o], Ds[1], ts);
                ts = fmaf(J2[o], Ds[2], ts);
                nds[o] = fmaf(-dt_, ts, Ds[o]);
            }
            #pragma unroll
            for (int o = 0; o < 3; ++o) { Dp[o] = ndp[o]; Ds[o] = nds[o]; }
        }
        px_ = fmaf(-dt_, vx, px_);
        py_ = fmaf(-dt_, vy, py_);
        pz_ = fmaf(-dt_, vz, pz_);
        tc_  -= dt_;
        off_ -= dt_;
    }

    // ---- output: q==0 lane of each point writes xyz + deform
    if (q == 0) {
        out[p*3+0] = px_; out[p*3+1] = py_; out[p*3+2] = pz_;
        float* o9 = out + (size_t)N*3 + (size_t)p*9;
        #pragma unroll
        for (int o = 0; o < 3; ++o) {
            o9[o*3+0] = Dp[o][0];
            o9[o*3+1] = Dp[o][1];
            o9[o*3+2] = Ds[o];
        }
    }
}

extern "C" void kernel_launch(void* const* d_in, const int* in_sizes, int n_in,
                              void* d_out, int out_size, void* d_ws, size_t ws_size,
                              hipStream_t stream) {
    const float* code = (const float*)d_in[0];
    const float* pos  = (const float*)d_in[1];
    const float* t1   = (const float*)d_in[2];
    const float* t2   = (const float*)d_in[3];
    const float* W1   = (const float*)d_in[4];
    const float* b1   = (const float*)d_in[5];
    const float* W2   = (const float*)d_in[6];
    const float* b2   = (const float*)d_in[7];
    const float* W3   = (const float*)d_in[8];
    const float* b3   = (const float*)d_in[9];
    float* out = (float*)d_out;
    const int N = in_sizes[1] / 3;           // 131072
    const int blocks = N / PPB;              // 2048
    const int pblocks = (N + 255) / 256;     // 512

    // Tiered workspace use:
    //   full (R22): 2-kernel fused pre-pass -> perm + wpack
    //   mid  (R19): 4-dispatch atomic pre-pass -> perm only
    //   none: identity mapping, in-kernel pack
    const size_t pb9 = ((size_t)pblocks * 9 * 4 + 15) & ~(size_t)15;
    const size_t need_full = pb9 + (size_t)WPACK_U4 * 16 + (size_t)N * 4;
    const size_t need_perm = 128 + (size_t)N * 4;
    int* perm = nullptr;
    uint4* wpack = nullptr;
    if (d_ws && ws_size >= need_full && pblocks <= HBLK) {
        unsigned* cnt2 = (unsigned*)d_ws;
        wpack = (uint4*)((char*)d_ws + pb9);
        perm  = (int*)((char*)d_ws + pb9 + (size_t)WPACK_U4 * 16);
        prep_hist2<<<pblocks + PACKB, 256, 0, stream>>>(t1, t2, cnt2, N, pblocks,
                                                        W1, W2, W3, b2, wpack);
        prep_scatter2<<<pblocks, 256, 0, stream>>>(t1, t2, cnt2, perm, N, pblocks);
    } else if (d_ws && ws_size >= need_perm) {
        unsigned* cnt = (unsigned*)d_ws;
        perm = (int*)((char*)d_ws + 128);
        hipMemsetAsync(d_ws, 0, 128, stream);
        prep_hist<<<pblocks, 256, 0, stream>>>(t1, t2, cnt, N);
        prep_prefix<<<1, 64, 0, stream>>>(cnt);
        prep_scatter<<<pblocks, 256, 0, stream>>>(t1, t2, cnt, perm, N);
    }
    velwarp<<<blocks, 256, 0, stream>>>(code, pos, t1, t2, W1, b1, W2, b2, W3, b3,
                                        out, perm, wpack, N);
}